// Round 1
// baseline (4442.825 us; speedup 1.0000x reference)
//
#include <hip/hip_runtime.h>

#define NNODES 20000
#define NEDGES 320000
#define DIM 256
#define DIM2 512
#define BN_EPS 1e-5f

// ---------------------------------------------------------------------------
// init: dst[i] = src[i]  (float4)
__global__ void copy4_kernel(const float* __restrict__ src, float* __restrict__ dst, int n4) {
    int i = blockIdx.x * blockDim.x + threadIdx.x;
    if (i < n4) ((float4*)dst)[i] = ((const float4*)src)[i];
}

// ---------------------------------------------------------------------------
// One wave (64 lanes) per edge; lane l handles 4 contiguous floats.
// Acc must be pre-initialized with x (so result = x + segment_sum(relu(x[src]+ea))).
__global__ void edge_kernel(const float* __restrict__ X, const int* __restrict__ ei,
                            const float* __restrict__ EA, float* __restrict__ Acc) {
    int tid = blockIdx.x * blockDim.x + threadIdx.x;
    int e = tid >> 6;
    if (e >= NEDGES) return;
    int l = tid & 63;
    int s = ei[e];
    int d = ei[NEDGES + e];
    float4 xv = *(const float4*)(X + (size_t)s * DIM + l * 4);
    float4 ev = *(const float4*)(EA + (size_t)e * DIM + l * 4);
    float m0 = fmaxf(xv.x + ev.x, 0.f);
    float m1 = fmaxf(xv.y + ev.y, 0.f);
    float m2 = fmaxf(xv.z + ev.z, 0.f);
    float m3 = fmaxf(xv.w + ev.w, 0.f);
    float* dp = Acc + (size_t)d * DIM + l * 4;
    atomicAdd(dp + 0, m0);
    atomicAdd(dp + 1, m1);
    atomicAdd(dp + 2, m2);
    atomicAdd(dp + 3, m3);
}

// ---------------------------------------------------------------------------
// C[M,Nc] = A[M,K] @ W[K,Nc] + bias, fp32, 64x64 tile, BK=16, 256 threads,
// 4x4 outputs per thread.
__global__ __launch_bounds__(256) void gemm_kernel(
        const float* __restrict__ A, const float* __restrict__ W,
        const float* __restrict__ bias, float* __restrict__ C,
        int M, int K, int Nc) {
    __shared__ float As[16][65];
    __shared__ float Ws[16][65];
    int tid = threadIdx.x;
    int tx = tid & 15, ty = tid >> 4;
    int r0 = blockIdx.y * 64, c0 = blockIdx.x * 64;
    float acc[4][4] = {};
    for (int k0 = 0; k0 < K; k0 += 16) {
        #pragma unroll
        for (int t = tid; t < 1024; t += 256) {
            int row = t >> 4, kk = t & 15;
            int gr = r0 + row;
            As[kk][row] = (gr < M) ? A[(size_t)gr * K + k0 + kk] : 0.f;
        }
        #pragma unroll
        for (int t = tid; t < 1024; t += 256) {
            int wr = t >> 6, wc = t & 63;
            Ws[wr][wc] = W[(size_t)(k0 + wr) * Nc + c0 + wc];
        }
        __syncthreads();
        #pragma unroll
        for (int kk = 0; kk < 16; ++kk) {
            float a[4], w[4];
            #pragma unroll
            for (int i = 0; i < 4; ++i) a[i] = As[kk][ty + i * 16];
            #pragma unroll
            for (int j = 0; j < 4; ++j) w[j] = Ws[kk][tx + j * 16];
            #pragma unroll
            for (int i = 0; i < 4; ++i)
                #pragma unroll
                for (int j = 0; j < 4; ++j)
                    acc[i][j] += a[i] * w[j];
        }
        __syncthreads();
    }
    #pragma unroll
    for (int i = 0; i < 4; ++i) {
        int gr = r0 + ty + i * 16;
        if (gr >= M) continue;
        #pragma unroll
        for (int j = 0; j < 4; ++j) {
            int gc = c0 + tx + j * 16;
            C[(size_t)gr * Nc + gc] = acc[i][j] + bias[gc];
        }
    }
}

// ---------------------------------------------------------------------------
// Column sums / sumsq over H[N,512]. stats[0..511]=sum, [512..1023]=sumsq.
// stats must be zeroed beforehand. Each thread owns 2 columns within its block.
__global__ void bn_stats_kernel(const float* __restrict__ H, float* __restrict__ stats) {
    int c = threadIdx.x;  // 0..255
    int rowsPer = (NNODES + gridDim.x - 1) / gridDim.x;
    int r0 = blockIdx.x * rowsPer;
    int r1 = min(r0 + rowsPer, NNODES);
    float s1 = 0.f, q1 = 0.f, s2 = 0.f, q2 = 0.f;
    for (int r = r0; r < r1; ++r) {
        float v1 = H[(size_t)r * DIM2 + c];
        float v2 = H[(size_t)r * DIM2 + c + 256];
        s1 += v1; q1 += v1 * v1;
        s2 += v2; q2 += v2 * v2;
    }
    atomicAdd(&stats[c], s1);
    atomicAdd(&stats[c + 256], s2);
    atomicAdd(&stats[DIM2 + c], q1);
    atomicAdd(&stats[DIM2 + c + 256], q2);
}

// In-place BN apply (+optional ReLU) on H[N,512].
__global__ void bn_apply_kernel(float* __restrict__ H, const float* __restrict__ stats,
                                const float* __restrict__ g, const float* __restrict__ be,
                                int relu) {
    const float invN = 1.0f / (float)NNODES;
    const int n4 = NNODES * DIM2 / 4;
    for (int i = blockIdx.x * blockDim.x + threadIdx.x; i < n4;
         i += gridDim.x * blockDim.x) {
        int cbase = (i * 4) & (DIM2 - 1);
        float4 v = ((float4*)H)[i];
        float vv[4] = {v.x, v.y, v.z, v.w};
        #pragma unroll
        for (int k = 0; k < 4; ++k) {
            int c = cbase + k;
            float mu = stats[c] * invN;
            float var = stats[DIM2 + c] * invN - mu * mu;
            float x = (vv[k] - mu) * rsqrtf(var + BN_EPS) * g[c] + be[c];
            if (relu) x = fmaxf(x, 0.f);
            vv[k] = x;
        }
        ((float4*)H)[i] = make_float4(vv[0], vv[1], vv[2], vv[3]);
    }
}

// ---------------------------------------------------------------------------
// sampled_z = noise*exp(logstd)+mean (out[0:ND]); KL reduced into out[3*ND]
// (pre-zeroed). mean at out+ND, logstd at out+2*ND already written.
__global__ void final_kernel(const float* __restrict__ noise, float* __restrict__ out) {
    const int ND = NNODES * DIM;
    const float* mean = out + ND;
    const float* logstd = out + 2 * ND;
    const int n4 = ND / 4;
    float kl = 0.f;
    for (int i = blockIdx.x * blockDim.x + threadIdx.x; i < n4;
         i += gridDim.x * blockDim.x) {
        float4 m = ((const float4*)mean)[i];
        float4 ls = ((const float4*)logstd)[i];
        float4 nz = ((const float4*)noise)[i];
        float e0 = expf(ls.x), e1 = expf(ls.y), e2 = expf(ls.z), e3 = expf(ls.w);
        float4 z;
        z.x = nz.x * e0 + m.x;
        z.y = nz.y * e1 + m.y;
        z.z = nz.z * e2 + m.z;
        z.w = nz.w * e3 + m.w;
        ((float4*)out)[i] = z;
        kl += (1.f + 2.f * ls.x - m.x * m.x - e0 * e0);
        kl += (1.f + 2.f * ls.y - m.y * m.y - e1 * e1);
        kl += (1.f + 2.f * ls.z - m.z * m.z - e2 * e2);
        kl += (1.f + 2.f * ls.w - m.w * m.w - e3 * e3);
    }
    #pragma unroll
    for (int o = 32; o > 0; o >>= 1) kl += __shfl_down(kl, o);
    if ((threadIdx.x & 63) == 0) {
        const float scale = 0.5f / ((float)NNODES * (float)NNODES);
        atomicAdd(out + 3 * ND, kl * scale);
    }
}

// ---------------------------------------------------------------------------
extern "C" void kernel_launch(void* const* d_in, const int* in_sizes, int n_in,
                              void* d_out, int out_size, void* d_ws, size_t ws_size,
                              hipStream_t stream) {
    const float* x     = (const float*)d_in[0];
    const int*   ei    = (const int*)d_in[1];
    const float* ea    = (const float*)d_in[2];
    const float* noise = (const float*)d_in[3];
    const float *W1[4], *b1[4], *g[4], *be[4], *W2[4], *b2[4];
    for (int i = 0; i < 4; ++i) {
        W1[i] = (const float*)d_in[4 + 6 * i];
        b1[i] = (const float*)d_in[5 + 6 * i];
        g[i]  = (const float*)d_in[6 + 6 * i];
        be[i] = (const float*)d_in[7 + 6 * i];
        W2[i] = (const float*)d_in[8 + 6 * i];
        b2[i] = (const float*)d_in[9 + 6 * i];
    }
    float* ws = (float*)d_ws;
    float* A     = ws;                            // [N,256]  h_in = x + agg
    float* B     = A + (size_t)NNODES * DIM;      // [N,512]  hidden
    float* H     = B + (size_t)NNODES * DIM2;     // [N,256]  layer-1 out
    float* H2    = H + (size_t)NNODES * DIM;      // [N,256]  layer-2 out
    float* stats = H2 + (size_t)NNODES * DIM;     // 1024
    float* out = (float*)d_out;
    const int ND = NNODES * DIM;

    const int copyGrid = (NNODES * DIM / 4 + 255) / 256;
    const int edgeGrid = (NEDGES * 64) / 256;
    dim3 g1grid(DIM2 / 64, (NNODES + 63) / 64);
    dim3 g2grid(DIM / 64, (NNODES + 63) / 64);

    auto mlp = [&](const float* in, int li, float* outp, int relu) {
        hipLaunchKernelGGL(gemm_kernel, g1grid, dim3(256), 0, stream,
                           in, W1[li], b1[li], B, NNODES, DIM, DIM2);
        hipMemsetAsync(stats, 0, 1024 * sizeof(float), stream);
        hipLaunchKernelGGL(bn_stats_kernel, dim3(160), dim3(256), 0, stream, B, stats);
        hipLaunchKernelGGL(bn_apply_kernel, dim3(2048), dim3(256), 0, stream,
                           B, stats, g[li], be[li], relu);
        hipLaunchKernelGGL(gemm_kernel, g2grid, dim3(256), 0, stream,
                           B, W2[li], b2[li], outp, NNODES, DIM2, DIM);
    };

    // layer 0: x -> H (relu)
    hipLaunchKernelGGL(copy4_kernel, dim3(copyGrid), dim3(256), 0, stream, x, A, NNODES * DIM / 4);
    hipLaunchKernelGGL(edge_kernel, dim3(edgeGrid), dim3(256), 0, stream, x, ei, ea, A);
    mlp(A, 0, H, 1);

    // layer 1: H -> H2 (relu)
    hipLaunchKernelGGL(copy4_kernel, dim3(copyGrid), dim3(256), 0, stream, H, A, NNODES * DIM / 4);
    hipLaunchKernelGGL(edge_kernel, dim3(edgeGrid), dim3(256), 0, stream, H, ei, ea, A);
    mlp(A, 1, H2, 1);

    // layers 2 & 3 share the gather/scatter on H2 — compute once
    hipLaunchKernelGGL(copy4_kernel, dim3(copyGrid), dim3(256), 0, stream, H2, A, NNODES * DIM / 4);
    hipLaunchKernelGGL(edge_kernel, dim3(edgeGrid), dim3(256), 0, stream, H2, ei, ea, A);
    mlp(A, 2, out + ND, 0);        // mean
    mlp(A, 3, out + 2 * ND, 0);    // logstd

    // final: sampled_z + kl
    hipMemsetAsync(out + 3 * ND, 0, sizeof(float), stream);
    hipLaunchKernelGGL(final_kernel, dim3(1280), dim3(256), 0, stream, noise, out);
}

// Round 2
// 1576.645 us; speedup vs baseline: 2.8179x; 2.8179x over previous
//
#include <hip/hip_runtime.h>

#define NNODES 20000
#define NEDGES 320000
#define DIM 256
#define DIM2 512
#define BN_EPS 1e-5f

// ---------------------------------------------------------------------------
// CSR build: histogram of dst
__global__ void hist_kernel(const int* __restrict__ ei, int* __restrict__ cnt) {
    int e = blockIdx.x * blockDim.x + threadIdx.x;
    if (e < NEDGES) atomicAdd(&cnt[ei[NEDGES + e]], 1);
}

// single-block exclusive scan of cnt[20000] -> off[20001], cur = off copy
__global__ __launch_bounds__(256) void scan_kernel(const int* __restrict__ cnt,
                                                   int* __restrict__ off,
                                                   int* __restrict__ cur) {
    int t = threadIdx.x;
    const int CH = (NNODES + 255) / 256;
    int b0 = t * CH, b1 = min(b0 + CH, NNODES);
    int s = 0;
    for (int i = b0; i < b1; ++i) s += cnt[i];
    __shared__ int sums[256];
    sums[t] = s;
    __syncthreads();
    if (t == 0) {
        int acc = 0;
        for (int i = 0; i < 256; ++i) { int tmp = sums[i]; sums[i] = acc; acc += tmp; }
        off[NNODES] = acc;
    }
    __syncthreads();
    int run = sums[t];
    for (int i = b0; i < b1; ++i) {
        off[i] = run;
        cur[i] = run;
        run += cnt[i];
    }
}

// scatter edge ids (+src) into dst buckets
__global__ void scatter_kernel(const int* __restrict__ ei, int* __restrict__ cur,
                               int* __restrict__ perm_e, int* __restrict__ perm_s) {
    int e = blockIdx.x * blockDim.x + threadIdx.x;
    if (e >= NEDGES) return;
    int d = ei[NEDGES + e];
    int pos = atomicAdd(&cur[d], 1);
    perm_e[pos] = e;
    perm_s[pos] = ei[e];
}

// ---------------------------------------------------------------------------
// One wave per node: A[n] = X[n] + sum_{edges e->n} relu(X[src]+EA[e]).
// No atomics; single 1KB write per node.
__global__ __launch_bounds__(256) void agg_kernel(
        const float* __restrict__ X, const float* __restrict__ EA,
        const int* __restrict__ off, const int* __restrict__ perm_e,
        const int* __restrict__ perm_s, float* __restrict__ A) {
    int wid = (blockIdx.x * blockDim.x + threadIdx.x) >> 6;
    if (wid >= NNODES) return;
    int l = threadIdx.x & 63;
    int s0 = off[wid], s1 = off[wid + 1];
    float4 acc = *(const float4*)(X + (size_t)wid * DIM + l * 4);
    for (int i = s0; i < s1; ++i) {
        int e = perm_e[i];
        int s = perm_s[i];
        float4 xv = *(const float4*)(X + (size_t)s * DIM + l * 4);
        float4 ev = *(const float4*)(EA + (size_t)e * DIM + l * 4);
        acc.x += fmaxf(xv.x + ev.x, 0.f);
        acc.y += fmaxf(xv.y + ev.y, 0.f);
        acc.z += fmaxf(xv.z + ev.z, 0.f);
        acc.w += fmaxf(xv.w + ev.w, 0.f);
    }
    *(float4*)(A + (size_t)wid * DIM + l * 4) = acc;
}

// ---------------------------------------------------------------------------
// C[M,Nc] = A[M,K] @ W[K,Nc] + bias, fp32, 64x64 tile, BK=16, 256 threads,
// 4x4 outputs per thread.
__global__ __launch_bounds__(256) void gemm_kernel(
        const float* __restrict__ A, const float* __restrict__ W,
        const float* __restrict__ bias, float* __restrict__ C,
        int M, int K, int Nc) {
    __shared__ float As[16][65];
    __shared__ float Ws[16][65];
    int tid = threadIdx.x;
    int tx = tid & 15, ty = tid >> 4;
    int r0 = blockIdx.y * 64, c0 = blockIdx.x * 64;
    float acc[4][4] = {};
    for (int k0 = 0; k0 < K; k0 += 16) {
        #pragma unroll
        for (int t = tid; t < 1024; t += 256) {
            int row = t >> 4, kk = t & 15;
            int gr = r0 + row;
            As[kk][row] = (gr < M) ? A[(size_t)gr * K + k0 + kk] : 0.f;
        }
        #pragma unroll
        for (int t = tid; t < 1024; t += 256) {
            int wr = t >> 6, wc = t & 63;
            Ws[wr][wc] = W[(size_t)(k0 + wr) * Nc + c0 + wc];
        }
        __syncthreads();
        #pragma unroll
        for (int kk = 0; kk < 16; ++kk) {
            float a[4], w[4];
            #pragma unroll
            for (int i = 0; i < 4; ++i) a[i] = As[kk][ty + i * 16];
            #pragma unroll
            for (int j = 0; j < 4; ++j) w[j] = Ws[kk][tx + j * 16];
            #pragma unroll
            for (int i = 0; i < 4; ++i)
                #pragma unroll
                for (int j = 0; j < 4; ++j)
                    acc[i][j] += a[i] * w[j];
        }
        __syncthreads();
    }
    #pragma unroll
    for (int i = 0; i < 4; ++i) {
        int gr = r0 + ty + i * 16;
        if (gr >= M) continue;
        #pragma unroll
        for (int j = 0; j < 4; ++j) {
            int gc = c0 + tx + j * 16;
            C[(size_t)gr * Nc + gc] = acc[i][j] + bias[gc];
        }
    }
}

// ---------------------------------------------------------------------------
// Column sums / sumsq over H[N,512]. stats[0..511]=sum, [512..1023]=sumsq.
__global__ void bn_stats_kernel(const float* __restrict__ H, float* __restrict__ stats) {
    int c = threadIdx.x;  // 0..255
    int rowsPer = (NNODES + gridDim.x - 1) / gridDim.x;
    int r0 = blockIdx.x * rowsPer;
    int r1 = min(r0 + rowsPer, NNODES);
    float s1 = 0.f, q1 = 0.f, s2 = 0.f, q2 = 0.f;
    for (int r = r0; r < r1; ++r) {
        float v1 = H[(size_t)r * DIM2 + c];
        float v2 = H[(size_t)r * DIM2 + c + 256];
        s1 += v1; q1 += v1 * v1;
        s2 += v2; q2 += v2 * v2;
    }
    atomicAdd(&stats[c], s1);
    atomicAdd(&stats[c + 256], s2);
    atomicAdd(&stats[DIM2 + c], q1);
    atomicAdd(&stats[DIM2 + c + 256], q2);
}

// In-place BN apply (+optional ReLU) on H[N,512].
__global__ void bn_apply_kernel(float* __restrict__ H, const float* __restrict__ stats,
                                const float* __restrict__ g, const float* __restrict__ be,
                                int relu) {
    const float invN = 1.0f / (float)NNODES;
    const int n4 = NNODES * DIM2 / 4;
    for (int i = blockIdx.x * blockDim.x + threadIdx.x; i < n4;
         i += gridDim.x * blockDim.x) {
        int cbase = (i * 4) & (DIM2 - 1);
        float4 v = ((float4*)H)[i];
        float vv[4] = {v.x, v.y, v.z, v.w};
        #pragma unroll
        for (int k = 0; k < 4; ++k) {
            int c = cbase + k;
            float mu = stats[c] * invN;
            float var = stats[DIM2 + c] * invN - mu * mu;
            float x = (vv[k] - mu) * rsqrtf(var + BN_EPS) * g[c] + be[c];
            if (relu) x = fmaxf(x, 0.f);
            vv[k] = x;
        }
        ((float4*)H)[i] = make_float4(vv[0], vv[1], vv[2], vv[3]);
    }
}

// ---------------------------------------------------------------------------
// sampled_z = noise*exp(logstd)+mean (out[0:ND]); KL reduced into out[3*ND].
__global__ void final_kernel(const float* __restrict__ noise, float* __restrict__ out) {
    const int ND = NNODES * DIM;
    const float* mean = out + ND;
    const float* logstd = out + 2 * ND;
    const int n4 = ND / 4;
    float kl = 0.f;
    for (int i = blockIdx.x * blockDim.x + threadIdx.x; i < n4;
         i += gridDim.x * blockDim.x) {
        float4 m = ((const float4*)mean)[i];
        float4 ls = ((const float4*)logstd)[i];
        float4 nz = ((const float4*)noise)[i];
        float e0 = expf(ls.x), e1 = expf(ls.y), e2 = expf(ls.z), e3 = expf(ls.w);
        float4 z;
        z.x = nz.x * e0 + m.x;
        z.y = nz.y * e1 + m.y;
        z.z = nz.z * e2 + m.z;
        z.w = nz.w * e3 + m.w;
        ((float4*)out)[i] = z;
        kl += (1.f + 2.f * ls.x - m.x * m.x - e0 * e0);
        kl += (1.f + 2.f * ls.y - m.y * m.y - e1 * e1);
        kl += (1.f + 2.f * ls.z - m.z * m.z - e2 * e2);
        kl += (1.f + 2.f * ls.w - m.w * m.w - e3 * e3);
    }
    #pragma unroll
    for (int o = 32; o > 0; o >>= 1) kl += __shfl_down(kl, o);
    if ((threadIdx.x & 63) == 0) {
        const float scale = 0.5f / ((float)NNODES * (float)NNODES);
        atomicAdd(out + 3 * ND, kl * scale);
    }
}

// ---------------------------------------------------------------------------
extern "C" void kernel_launch(void* const* d_in, const int* in_sizes, int n_in,
                              void* d_out, int out_size, void* d_ws, size_t ws_size,
                              hipStream_t stream) {
    const float* x     = (const float*)d_in[0];
    const int*   ei    = (const int*)d_in[1];
    const float* ea    = (const float*)d_in[2];
    const float* noise = (const float*)d_in[3];
    const float *W1[4], *b1[4], *g[4], *be[4], *W2[4], *b2[4];
    for (int i = 0; i < 4; ++i) {
        W1[i] = (const float*)d_in[4 + 6 * i];
        b1[i] = (const float*)d_in[5 + 6 * i];
        g[i]  = (const float*)d_in[6 + 6 * i];
        be[i] = (const float*)d_in[7 + 6 * i];
        W2[i] = (const float*)d_in[8 + 6 * i];
        b2[i] = (const float*)d_in[9 + 6 * i];
    }
    float* ws = (float*)d_ws;
    float* A     = ws;                            // [N,256]  h_in = x + agg
    float* B     = A + (size_t)NNODES * DIM;      // [N,512]  hidden
    float* H     = B + (size_t)NNODES * DIM2;     // [N,256]  layer-1 out
    float* H2    = H + (size_t)NNODES * DIM;      // [N,256]  layer-2 out
    float* stats = H2 + (size_t)NNODES * DIM;     // 1024
    int* cnt    = (int*)(stats + 1024);           // 20000
    int* off    = cnt + NNODES;                   // 20001 (+pad)
    int* cur    = off + NNODES + 8;               // 20000
    int* perm_e = cur + NNODES;                   // 320000
    int* perm_s = perm_e + NEDGES;                // 320000
    float* out = (float*)d_out;
    const int ND = NNODES * DIM;

    const int edgeGrid = (NEDGES + 255) / 256;
    const int aggGrid = (NNODES * 64) / 256;
    dim3 g1grid(DIM2 / 64, (NNODES + 63) / 64);
    dim3 g2grid(DIM / 64, (NNODES + 63) / 64);

    // --- build dst-CSR once (reused for all 3 aggregation passes)
    hipMemsetAsync(cnt, 0, NNODES * sizeof(int), stream);
    hipLaunchKernelGGL(hist_kernel, dim3(edgeGrid), dim3(256), 0, stream, ei, cnt);
    hipLaunchKernelGGL(scan_kernel, dim3(1), dim3(256), 0, stream, cnt, off, cur);
    hipLaunchKernelGGL(scatter_kernel, dim3(edgeGrid), dim3(256), 0, stream,
                       ei, cur, perm_e, perm_s);

    auto mlp = [&](const float* in, int li, float* outp, int relu) {
        hipLaunchKernelGGL(gemm_kernel, g1grid, dim3(256), 0, stream,
                           in, W1[li], b1[li], B, NNODES, DIM, DIM2);
        hipMemsetAsync(stats, 0, 1024 * sizeof(float), stream);
        hipLaunchKernelGGL(bn_stats_kernel, dim3(160), dim3(256), 0, stream, B, stats);
        hipLaunchKernelGGL(bn_apply_kernel, dim3(2048), dim3(256), 0, stream,
                           B, stats, g[li], be[li], relu);
        hipLaunchKernelGGL(gemm_kernel, g2grid, dim3(256), 0, stream,
                           B, W2[li], b2[li], outp, NNODES, DIM2, DIM);
    };

    // layer 0: x -> H (relu)
    hipLaunchKernelGGL(agg_kernel, dim3(aggGrid), dim3(256), 0, stream,
                       x, ea, off, perm_e, perm_s, A);
    mlp(A, 0, H, 1);

    // layer 1: H -> H2 (relu)
    hipLaunchKernelGGL(agg_kernel, dim3(aggGrid), dim3(256), 0, stream,
                       H, ea, off, perm_e, perm_s, A);
    mlp(A, 1, H2, 1);

    // layers 2 & 3 share the gather/scatter on H2 — compute once
    hipLaunchKernelGGL(agg_kernel, dim3(aggGrid), dim3(256), 0, stream,
                       H2, ea, off, perm_e, perm_s, A);
    mlp(A, 2, out + ND, 0);        // mean
    mlp(A, 3, out + 2 * ND, 0);    // logstd

    // final: sampled_z + kl
    hipMemsetAsync(out + 3 * ND, 0, sizeof(float), stream);
    hipLaunchKernelGGL(final_kernel, dim3(1280), dim3(256), 0, stream, noise, out);
}

// Round 3
// 826.629 us; speedup vs baseline: 5.3746x; 1.9073x over previous
//
#include <hip/hip_runtime.h>

#define NNODES 20000
#define NEDGES 320000
#define DIM 256
#define DIM2 512
#define MPAD 20096          // 157 * 128
#define BN_EPS 1e-5f

typedef __attribute__((ext_vector_type(8))) short bf16x8;
typedef __attribute__((ext_vector_type(4))) float f32x4;

__device__ inline ushort f2bf(float f) {
    unsigned u = __float_as_uint(f);
    u += 0x7FFF + ((u >> 16) & 1);   // round-to-nearest-even
    return (ushort)(u >> 16);
}

// ---------------------------------------------------------------------------
// CSR build: histogram of dst
__global__ void hist_kernel(const int* __restrict__ ei, int* __restrict__ cnt) {
    int e = blockIdx.x * blockDim.x + threadIdx.x;
    if (e < NEDGES) atomicAdd(&cnt[ei[NEDGES + e]], 1);
}

__global__ __launch_bounds__(256) void scan_kernel(const int* __restrict__ cnt,
                                                   int* __restrict__ off,
                                                   int* __restrict__ cur) {
    int t = threadIdx.x;
    const int CH = (NNODES + 255) / 256;
    int b0 = t * CH, b1 = min(b0 + CH, NNODES);
    int s = 0;
    for (int i = b0; i < b1; ++i) s += cnt[i];
    __shared__ int sums[256];
    sums[t] = s;
    __syncthreads();
    if (t == 0) {
        int acc = 0;
        for (int i = 0; i < 256; ++i) { int tmp = sums[i]; sums[i] = acc; acc += tmp; }
        off[NNODES] = acc;
    }
    __syncthreads();
    int run = sums[t];
    for (int i = b0; i < b1; ++i) {
        off[i] = run;
        cur[i] = run;
        run += cnt[i];
    }
}

__global__ void scatter_kernel(const int* __restrict__ ei, int* __restrict__ cur,
                               int* __restrict__ perm_e, int* __restrict__ perm_s) {
    int e = blockIdx.x * blockDim.x + threadIdx.x;
    if (e >= NEDGES) return;
    int d = ei[NEDGES + e];
    int pos = atomicAdd(&cur[d], 1);
    perm_e[pos] = e;
    perm_s[pos] = ei[e];
}

// ---------------------------------------------------------------------------
// One wave per node: A16[n] = bf16( X[n] + sum_{e->n} relu(X[src]+EA[e]) )
__global__ __launch_bounds__(256) void agg_kernel(
        const float* __restrict__ X, const float* __restrict__ EA,
        const int* __restrict__ off, const int* __restrict__ perm_e,
        const int* __restrict__ perm_s, ushort* __restrict__ A16) {
    int wid = (blockIdx.x * blockDim.x + threadIdx.x) >> 6;
    if (wid >= NNODES) return;
    int l = threadIdx.x & 63;
    int s0 = off[wid], s1 = off[wid + 1];
    float4 acc = *(const float4*)(X + (size_t)wid * DIM + l * 4);
    for (int i = s0; i < s1; ++i) {
        int e = perm_e[i];
        int s = perm_s[i];
        float4 xv = *(const float4*)(X + (size_t)s * DIM + l * 4);
        float4 ev = *(const float4*)(EA + (size_t)e * DIM + l * 4);
        acc.x += fmaxf(xv.x + ev.x, 0.f);
        acc.y += fmaxf(xv.y + ev.y, 0.f);
        acc.z += fmaxf(xv.z + ev.z, 0.f);
        acc.w += fmaxf(xv.w + ev.w, 0.f);
    }
    ushort4 o;
    o.x = f2bf(acc.x); o.y = f2bf(acc.y); o.z = f2bf(acc.z); o.w = f2bf(acc.w);
    *(ushort4*)(A16 + (size_t)wid * DIM + l * 4) = o;
}

// ---------------------------------------------------------------------------
// Weight convert+transpose: out[Nc][K] bf16 = in[K][Nc] fp32, all 8 weights.
struct WPtrs {
    const float* w[8];
    ushort* o[8];
    int K[8];
    int Nc[8];
};
__global__ __launch_bounds__(256) void wconv_kernel(WPtrs p) {
    int w = blockIdx.x >> 9;                       // 512 blocks / weight
    int idx = ((blockIdx.x & 511) << 8) + threadIdx.x;  // 0..131071
    int K = p.K[w], Nc = p.Nc[w];
    int oc = idx / K, ok = idx - oc * K;           // out[oc][ok] = in[ok][oc]
    p.o[w][idx] = f2bf(p.w[w][(size_t)ok * Nc + oc]);
}

// ---------------------------------------------------------------------------
// MFMA GEMM: C[gr][gc] = sum_k A16[gr][k] * WT[gc][k]  + bias[gc]
// A16: [MPAD][K] bf16 row-major; WT: [Nc][K] bf16 row-major (pre-transposed).
// Block 128x128, BK=64, 256 threads = 4 waves (2x2), 64x64 per wave.
template<int K>
__global__ __launch_bounds__(256) void mfma_gemm(
        const ushort* __restrict__ A16, const ushort* __restrict__ WT,
        const float* __restrict__ bias, float* __restrict__ C,
        int Nc, int Mlimit) {
    __shared__ ushort As[128 * 72];   // stride 72 bf16 (144B, 16B-aligned rows)
    __shared__ ushort Bs[128 * 72];
    const int tid = threadIdx.x;
    const int lane = tid & 63;
    const int wv = tid >> 6;                  // 0..3
    const int wr = wv >> 1, wc = wv & 1;      // 2x2 wave grid
    const int l15 = lane & 15, lhi = lane >> 4;
    const int r0 = blockIdx.y * 128, c0 = blockIdx.x * 128;
    const int srow = tid >> 1;                // staging row 0..127
    const int sseg = (tid & 1) * 4;           // 4x 16B segments per thread per tile

    f32x4 acc[4][4] = {};

    for (int k0 = 0; k0 < K; k0 += 64) {
        const ushort* ga = A16 + (size_t)(r0 + srow) * K + k0 + sseg * 8;
        const ushort* gb = WT + (size_t)(c0 + srow) * K + k0 + sseg * 8;
        ushort* la = As + srow * 72 + sseg * 8;
        ushort* lb = Bs + srow * 72 + sseg * 8;
        #pragma unroll
        for (int i = 0; i < 4; ++i) {
            *(uint4*)(la + i * 8) = *(const uint4*)(ga + i * 8);
            *(uint4*)(lb + i * 8) = *(const uint4*)(gb + i * 8);
        }
        __syncthreads();
        #pragma unroll
        for (int kk = 0; kk < 2; ++kk) {
            bf16x8 a[4], b[4];
            #pragma unroll
            for (int m = 0; m < 4; ++m)
                a[m] = *(const bf16x8*)(As + (wr * 64 + m * 16 + l15) * 72 + kk * 32 + lhi * 8);
            #pragma unroll
            for (int n = 0; n < 4; ++n)
                b[n] = *(const bf16x8*)(Bs + (wc * 64 + n * 16 + l15) * 72 + kk * 32 + lhi * 8);
            #pragma unroll
            for (int m = 0; m < 4; ++m)
                #pragma unroll
                for (int n = 0; n < 4; ++n)
                    acc[m][n] = __builtin_amdgcn_mfma_f32_16x16x32_bf16(
                        a[m], b[n], acc[m][n], 0, 0, 0);
        }
        __syncthreads();
    }

    // epilogue: C/D layout col = lane&15, row = (lane>>4)*4 + reg
    #pragma unroll
    for (int m = 0; m < 4; ++m) {
        #pragma unroll
        for (int q = 0; q < 4; ++q) {
            int gr = r0 + wr * 64 + m * 16 + lhi * 4 + q;
            if (gr >= Mlimit) continue;
            #pragma unroll
            for (int n = 0; n < 4; ++n) {
                int gc = c0 + wc * 64 + n * 16 + l15;
                C[(size_t)gr * Nc + gc] = acc[m][n][q] + bias[gc];
            }
        }
    }
}

// ---------------------------------------------------------------------------
// Column sums / sumsq over B[N,512] fp32.
__global__ void bn_stats_kernel(const float* __restrict__ H, float* __restrict__ stats) {
    int c = threadIdx.x;  // 0..255
    int rowsPer = (NNODES + gridDim.x - 1) / gridDim.x;
    int r0 = blockIdx.x * rowsPer;
    int r1 = min(r0 + rowsPer, NNODES);
    float s1 = 0.f, q1 = 0.f, s2 = 0.f, q2 = 0.f;
    for (int r = r0; r < r1; ++r) {
        float v1 = H[(size_t)r * DIM2 + c];
        float v2 = H[(size_t)r * DIM2 + c + 256];
        s1 += v1; q1 += v1 * v1;
        s2 += v2; q2 += v2 * v2;
    }
    atomicAdd(&stats[c], s1);
    atomicAdd(&stats[c + 256], s2);
    atomicAdd(&stats[DIM2 + c], q1);
    atomicAdd(&stats[DIM2 + c + 256], q2);
}

// BN apply (+optional ReLU): read fp32 B, write bf16 B16.
__global__ void bn_apply_kernel(const float* __restrict__ H, ushort* __restrict__ H16,
                                const float* __restrict__ stats,
                                const float* __restrict__ g, const float* __restrict__ be,
                                int relu) {
    const float invN = 1.0f / (float)NNODES;
    const int n4 = NNODES * DIM2 / 4;
    for (int i = blockIdx.x * blockDim.x + threadIdx.x; i < n4;
         i += gridDim.x * blockDim.x) {
        int cbase = (i * 4) & (DIM2 - 1);
        float4 v = ((const float4*)H)[i];
        float vv[4] = {v.x, v.y, v.z, v.w};
        ushort4 o;
        #pragma unroll
        for (int k = 0; k < 4; ++k) {
            int c = cbase + k;
            float mu = stats[c] * invN;
            float var = stats[DIM2 + c] * invN - mu * mu;
            float x = (vv[k] - mu) * rsqrtf(var + BN_EPS) * g[c] + be[c];
            if (relu) x = fmaxf(x, 0.f);
            vv[k] = x;
        }
        o.x = f2bf(vv[0]); o.y = f2bf(vv[1]); o.z = f2bf(vv[2]); o.w = f2bf(vv[3]);
        ((ushort4*)H16)[i] = o;
    }
}

// ---------------------------------------------------------------------------
// sampled_z = noise*exp(logstd)+mean; KL into out[3*ND].
__global__ void final_kernel(const float* __restrict__ noise, float* __restrict__ out) {
    const int ND = NNODES * DIM;
    const float* mean = out + ND;
    const float* logstd = out + 2 * ND;
    const int n4 = ND / 4;
    float kl = 0.f;
    for (int i = blockIdx.x * blockDim.x + threadIdx.x; i < n4;
         i += gridDim.x * blockDim.x) {
        float4 m = ((const float4*)mean)[i];
        float4 ls = ((const float4*)logstd)[i];
        float4 nz = ((const float4*)noise)[i];
        float e0 = expf(ls.x), e1 = expf(ls.y), e2 = expf(ls.z), e3 = expf(ls.w);
        float4 z;
        z.x = nz.x * e0 + m.x;
        z.y = nz.y * e1 + m.y;
        z.z = nz.z * e2 + m.z;
        z.w = nz.w * e3 + m.w;
        ((float4*)out)[i] = z;
        kl += (1.f + 2.f * ls.x - m.x * m.x - e0 * e0);
        kl += (1.f + 2.f * ls.y - m.y * m.y - e1 * e1);
        kl += (1.f + 2.f * ls.z - m.z * m.z - e2 * e2);
        kl += (1.f + 2.f * ls.w - m.w * m.w - e3 * e3);
    }
    #pragma unroll
    for (int o = 32; o > 0; o >>= 1) kl += __shfl_down(kl, o);
    if ((threadIdx.x & 63) == 0) {
        const float scale = 0.5f / ((float)NNODES * (float)NNODES);
        atomicAdd(out + 3 * ND, kl * scale);
    }
}

// ---------------------------------------------------------------------------
extern "C" void kernel_launch(void* const* d_in, const int* in_sizes, int n_in,
                              void* d_out, int out_size, void* d_ws, size_t ws_size,
                              hipStream_t stream) {
    const float* x     = (const float*)d_in[0];
    const int*   ei    = (const int*)d_in[1];
    const float* ea    = (const float*)d_in[2];
    const float* noise = (const float*)d_in[3];
    const float *W1[4], *b1[4], *g[4], *be[4], *W2[4], *b2[4];
    for (int i = 0; i < 4; ++i) {
        W1[i] = (const float*)d_in[4 + 6 * i];
        b1[i] = (const float*)d_in[5 + 6 * i];
        g[i]  = (const float*)d_in[6 + 6 * i];
        be[i] = (const float*)d_in[7 + 6 * i];
        W2[i] = (const float*)d_in[8 + 6 * i];
        b2[i] = (const float*)d_in[9 + 6 * i];
    }
    float* ws = (float*)d_ws;
    float* B     = ws;                              // [MPAD,512] fp32
    float* H     = B + (size_t)MPAD * DIM2;         // [MPAD,256] fp32
    float* H2    = H + (size_t)MPAD * DIM;          // [MPAD,256] fp32
    float* stats = H2 + (size_t)MPAD * DIM;         // 1024
    ushort* A16  = (ushort*)(stats + 1024);         // [MPAD,256] bf16
    ushort* B16  = A16 + (size_t)MPAD * DIM;        // [MPAD,512] bf16
    ushort* WT16 = B16 + (size_t)MPAD * DIM2;       // 8 x 131072 bf16
    int* cnt    = (int*)(WT16 + 8 * 131072);
    int* off    = cnt + NNODES;
    int* cur    = off + NNODES + 8;
    int* perm_e = cur + NNODES;
    int* perm_s = perm_e + NEDGES;
    float* out = (float*)d_out;
    const int ND = NNODES * DIM;

    const int edgeGrid = (NEDGES + 255) / 256;
    const int aggGrid = (NNODES * 64) / 256;

    // --- weight convert + transpose (once)
    WPtrs wp;
    for (int i = 0; i < 4; ++i) {
        wp.w[i] = W1[i];     wp.o[i] = WT16 + (size_t)i * 131072;
        wp.K[i] = DIM;       wp.Nc[i] = DIM2;                       // W1T [512][256]
        wp.w[4 + i] = W2[i]; wp.o[4 + i] = WT16 + (size_t)(4 + i) * 131072;
        wp.K[4 + i] = DIM2;  wp.Nc[4 + i] = DIM;                    // W2T [256][512]
    }
    hipLaunchKernelGGL(wconv_kernel, dim3(8 * 512), dim3(256), 0, stream, wp);

    // --- build dst-CSR once
    hipMemsetAsync(cnt, 0, NNODES * sizeof(int), stream);
    hipLaunchKernelGGL(hist_kernel, dim3(edgeGrid), dim3(256), 0, stream, ei, cnt);
    hipLaunchKernelGGL(scan_kernel, dim3(1), dim3(256), 0, stream, cnt, off, cur);
    hipLaunchKernelGGL(scatter_kernel, dim3(edgeGrid), dim3(256), 0, stream,
                       ei, cur, perm_e, perm_s);

    auto mlp = [&](int li, float* outp, int relu) {
        hipLaunchKernelGGL((mfma_gemm<DIM>), dim3(DIM2 / 128, MPAD / 128), dim3(256), 0, stream,
                           A16, WT16 + (size_t)li * 131072, b1[li], B, DIM2, NNODES);
        hipMemsetAsync(stats, 0, 1024 * sizeof(float), stream);
        hipLaunchKernelGGL(bn_stats_kernel, dim3(160), dim3(256), 0, stream, B, stats);
        hipLaunchKernelGGL(bn_apply_kernel, dim3(2048), dim3(256), 0, stream,
                           B, B16, stats, g[li], be[li], relu);
        hipLaunchKernelGGL((mfma_gemm<DIM2>), dim3(DIM / 128, MPAD / 128), dim3(256), 0, stream,
                           B16, WT16 + (size_t)(4 + li) * 131072, b2[li], outp, DIM, NNODES);
    };

    // layer 0: x -> H (relu)
    hipLaunchKernelGGL(agg_kernel, dim3(aggGrid), dim3(256), 0, stream,
                       x, ea, off, perm_e, perm_s, A16);
    mlp(0, H, 1);

    // layer 1: H -> H2 (relu)
    hipLaunchKernelGGL(agg_kernel, dim3(aggGrid), dim3(256), 0, stream,
                       H, ea, off, perm_e, perm_s, A16);
    mlp(1, H2, 1);

    // layers 2 & 3 share the aggregation on H2 — compute once
    hipLaunchKernelGGL(agg_kernel, dim3(aggGrid), dim3(256), 0, stream,
                       H2, ea, off, perm_e, perm_s, A16);
    mlp(2, out + ND, 0);        // mean
    mlp(3, out + 2 * ND, 0);    // logstd

    // final: sampled_z + kl
    hipMemsetAsync(out + 3 * ND, 0, sizeof(float), stream);
    hipLaunchKernelGGL(final_kernel, dim3(1280), dim3(256), 0, stream, noise, out);
}

// Round 4
// 618.069 us; speedup vs baseline: 7.1882x; 1.3374x over previous
//
#include <hip/hip_runtime.h>

#define NNODES 20000
#define NEDGES 320000
#define DIM 256
#define DIM2 512
#define MPAD 20096          // 157 * 128
#define BN_EPS 1e-5f
#define NDTOT (NNODES * DIM)

typedef __attribute__((ext_vector_type(8))) short bf16x8;
typedef __attribute__((ext_vector_type(4))) float f32x4;

__device__ inline ushort f2bf(float f) {
    unsigned u = __float_as_uint(f);
    u += 0x7FFF + ((u >> 16) & 1);   // round-to-nearest-even
    return (ushort)(u >> 16);
}
__device__ inline float bf2f(ushort u) {
    return __uint_as_float(((unsigned)u) << 16);
}

// ---------------------------------------------------------------------------
// CSR build
__global__ void hist_kernel(const int* __restrict__ ei, int* __restrict__ cnt) {
    int e = blockIdx.x * blockDim.x + threadIdx.x;
    if (e < NEDGES) atomicAdd(&cnt[ei[NEDGES + e]], 1);
}

__global__ __launch_bounds__(256) void scan_kernel(const int* __restrict__ cnt,
                                                   int* __restrict__ off,
                                                   int* __restrict__ cur) {
    int t = threadIdx.x;
    const int CH = (NNODES + 255) / 256;
    int b0 = t * CH, b1 = min(b0 + CH, NNODES);
    int s = 0;
    for (int i = b0; i < b1; ++i) s += cnt[i];
    __shared__ int sums[256];
    sums[t] = s;
    __syncthreads();
    if (t == 0) {
        int acc = 0;
        for (int i = 0; i < 256; ++i) { int tmp = sums[i]; sums[i] = acc; acc += tmp; }
        off[NNODES] = acc;
    }
    __syncthreads();
    int run = sums[t];
    for (int i = b0; i < b1; ++i) {
        off[i] = run;
        cur[i] = run;
        run += cnt[i];
    }
}

__global__ void scatter_kernel(const int* __restrict__ ei, int* __restrict__ cur,
                               int* __restrict__ perm_e, int* __restrict__ perm_s) {
    int e = blockIdx.x * blockDim.x + threadIdx.x;
    if (e >= NEDGES) return;
    int d = ei[NEDGES + e];
    int pos = atomicAdd(&cur[d], 1);
    perm_e[pos] = e;
    perm_s[pos] = ei[e];
}

// ---------------------------------------------------------------------------
// One wave per node: A16[n] = bf16( X[n] + sum_{e->n} relu(X[src]+EA[e]) ).
// XF32: X is fp32 (else bf16). EA32: edge_attr fp32 (else bf16).
// WEA: additionally write bf16 copy of EA rows (pass-1 conversion).
template<bool XF32, bool EA32, bool WEA>
__global__ __launch_bounds__(256) void agg_kernel(
        const float* __restrict__ Xf, const ushort* __restrict__ Xh,
        const float* __restrict__ EAf, const ushort* __restrict__ EAh,
        ushort* __restrict__ EAout,
        const int* __restrict__ off, const int* __restrict__ perm_e,
        const int* __restrict__ perm_s, ushort* __restrict__ A16) {
    int wid = (blockIdx.x * blockDim.x + threadIdx.x) >> 6;
    if (wid >= NNODES) return;
    int l = threadIdx.x & 63;
    int s0 = off[wid], s1 = off[wid + 1];
    float4 acc;
    if (XF32) {
        acc = *(const float4*)(Xf + (size_t)wid * DIM + l * 4);
    } else {
        ushort4 v = *(const ushort4*)(Xh + (size_t)wid * DIM + l * 4);
        acc = make_float4(bf2f(v.x), bf2f(v.y), bf2f(v.z), bf2f(v.w));
    }
    #pragma unroll 2
    for (int i = s0; i < s1; ++i) {
        int e = perm_e[i];
        int s = perm_s[i];
        float4 xr, er;
        if (XF32) {
            xr = *(const float4*)(Xf + (size_t)s * DIM + l * 4);
        } else {
            ushort4 v = *(const ushort4*)(Xh + (size_t)s * DIM + l * 4);
            xr = make_float4(bf2f(v.x), bf2f(v.y), bf2f(v.z), bf2f(v.w));
        }
        if (EA32) {
            er = *(const float4*)(EAf + (size_t)e * DIM + l * 4);
        } else {
            ushort4 v = *(const ushort4*)(EAh + (size_t)e * DIM + l * 4);
            er = make_float4(bf2f(v.x), bf2f(v.y), bf2f(v.z), bf2f(v.w));
        }
        if (WEA) {
            ushort4 o;
            o.x = f2bf(er.x); o.y = f2bf(er.y); o.z = f2bf(er.z); o.w = f2bf(er.w);
            *(ushort4*)(EAout + (size_t)e * DIM + l * 4) = o;
        }
        acc.x += fmaxf(xr.x + er.x, 0.f);
        acc.y += fmaxf(xr.y + er.y, 0.f);
        acc.z += fmaxf(xr.z + er.z, 0.f);
        acc.w += fmaxf(xr.w + er.w, 0.f);
    }
    ushort4 o;
    o.x = f2bf(acc.x); o.y = f2bf(acc.y); o.z = f2bf(acc.z); o.w = f2bf(acc.w);
    *(ushort4*)(A16 + (size_t)wid * DIM + l * 4) = o;
}

// ---------------------------------------------------------------------------
// Weight convert+transpose: out[Nc][K] bf16 = in[K][Nc] fp32, all 8 weights.
struct WPtrs {
    const float* w[8];
    ushort* o[8];
    int K[8];
    int Nc[8];
};
__global__ __launch_bounds__(256) void wconv_kernel(WPtrs p) {
    int w = blockIdx.x >> 9;
    int idx = ((blockIdx.x & 511) << 8) + threadIdx.x;
    int K = p.K[w], Nc = p.Nc[w];
    int oc = idx / K, ok = idx - oc * K;
    p.o[w][idx] = f2bf(p.w[w][(size_t)ok * Nc + oc]);
}

// ---------------------------------------------------------------------------
// MFMA GEMM: out[gr][gc] = sum_k A16[gr][k] * WT[gc][k] + bias[gc]
// A16: [*][lda] bf16; WT: [Nc][K] bf16 (pre-transposed).
// Block 128x128, BK=64, 4 waves (2x2), 64x64/wave.
// OUT_BF16: write ushort C16 else float Cf.
// STATS: accumulate per-column sum/sumsq (rows < Mlimit) into stats[0..Nc-1]
//        and stats[Nc..2Nc-1] (must be pre-zeroed). bias split at col 512
//        (bias2 used for gc >= 512; for Nc<=512 pass bias twice).
template<int K, bool OUT_BF16, bool STATS>
__global__ __launch_bounds__(256) void mfma_gemm(
        const ushort* __restrict__ A16, int lda,
        const ushort* __restrict__ WT,
        const float* __restrict__ bias, const float* __restrict__ bias2,
        float* __restrict__ Cf, ushort* __restrict__ C16, int ldc,
        float* __restrict__ stats, int Nc, int Mlimit) {
    __shared__ ushort As[128 * 72];
    __shared__ ushort Bs[128 * 72];
    const int tid = threadIdx.x;
    const int lane = tid & 63;
    const int wv = tid >> 6, wr = wv >> 1, wc = wv & 1;
    const int l15 = lane & 15, lhi = lane >> 4;
    const int r0 = blockIdx.y * 128, c0 = blockIdx.x * 128;
    const int srow = tid >> 1;
    const int sseg = (tid & 1) * 4;

    f32x4 acc[4][4] = {};

    for (int k0 = 0; k0 < K; k0 += 64) {
        const ushort* ga = A16 + (size_t)(r0 + srow) * lda + k0 + sseg * 8;
        const ushort* gb = WT + (size_t)(c0 + srow) * K + k0 + sseg * 8;
        ushort* la = As + srow * 72 + sseg * 8;
        ushort* lb = Bs + srow * 72 + sseg * 8;
        #pragma unroll
        for (int i = 0; i < 4; ++i) {
            *(uint4*)(la + i * 8) = *(const uint4*)(ga + i * 8);
            *(uint4*)(lb + i * 8) = *(const uint4*)(gb + i * 8);
        }
        __syncthreads();
        #pragma unroll
        for (int kk = 0; kk < 2; ++kk) {
            bf16x8 a[4], b[4];
            #pragma unroll
            for (int m = 0; m < 4; ++m)
                a[m] = *(const bf16x8*)(As + (wr * 64 + m * 16 + l15) * 72 + kk * 32 + lhi * 8);
            #pragma unroll
            for (int n = 0; n < 4; ++n)
                b[n] = *(const bf16x8*)(Bs + (wc * 64 + n * 16 + l15) * 72 + kk * 32 + lhi * 8);
            #pragma unroll
            for (int m = 0; m < 4; ++m)
                #pragma unroll
                for (int n = 0; n < 4; ++n)
                    acc[m][n] = __builtin_amdgcn_mfma_f32_16x16x32_bf16(
                        a[m], b[n], acc[m][n], 0, 0, 0);
        }
        __syncthreads();
    }

    float bv[4];
    #pragma unroll
    for (int n = 0; n < 4; ++n) {
        int gc = c0 + wc * 64 + n * 16 + l15;
        bv[n] = (gc < DIM2) ? bias[gc] : bias2[gc - DIM2];
    }
    float sm[4] = {0.f, 0.f, 0.f, 0.f}, sq[4] = {0.f, 0.f, 0.f, 0.f};
    #pragma unroll
    for (int m = 0; m < 4; ++m) {
        #pragma unroll
        for (int q = 0; q < 4; ++q) {
            int gr = r0 + wr * 64 + m * 16 + lhi * 4 + q;
            if (gr >= Mlimit) continue;
            #pragma unroll
            for (int n = 0; n < 4; ++n) {
                int gc = c0 + wc * 64 + n * 16 + l15;
                float v = acc[m][n][q] + bv[n];
                if (OUT_BF16) C16[(size_t)gr * ldc + gc] = f2bf(v);
                else          Cf[(size_t)gr * ldc + gc] = v;
                if (STATS) { sm[n] += v; sq[n] += v * v; }
            }
        }
    }
    if (STATS) {
        #pragma unroll
        for (int n = 0; n < 4; ++n) {
            float sv = sm[n], qv = sq[n];
            sv += __shfl_xor(sv, 16); sv += __shfl_xor(sv, 32);
            qv += __shfl_xor(qv, 16); qv += __shfl_xor(qv, 32);
            if (lane < 16) {
                int gc = c0 + wc * 64 + n * 16 + l15;
                atomicAdd(&stats[gc], sv);
                atomicAdd(&stats[Nc + gc], qv);
            }
        }
    }
}

// ---------------------------------------------------------------------------
// BN apply in-place on bf16 [NNODES, NCOLS]; gamma/beta split at col 512.
template<int NCOLS>
__global__ __launch_bounds__(256) void bn_apply_kernel(
        ushort* __restrict__ H16, const float* __restrict__ stats,
        const float* __restrict__ g0, const float* __restrict__ be0,
        const float* __restrict__ g1, const float* __restrict__ be1,
        int relu) {
    const float invN = 1.0f / (float)NNODES;
    const int n4 = NNODES * NCOLS / 4;
    for (int i = blockIdx.x * blockDim.x + threadIdx.x; i < n4;
         i += gridDim.x * blockDim.x) {
        int cbase = (i * 4) & (NCOLS - 1);
        ushort4 u = ((const ushort4*)H16)[i];
        float vv[4] = {bf2f(u.x), bf2f(u.y), bf2f(u.z), bf2f(u.w)};
        #pragma unroll
        for (int k = 0; k < 4; ++k) {
            int c = cbase + k;
            const float* gp = (c < DIM2) ? g0 : g1;
            const float* bp = (c < DIM2) ? be0 : be1;
            float mu = stats[c] * invN;
            float var = stats[NCOLS + c] * invN - mu * mu;
            float x = (vv[k] - mu) * rsqrtf(var + BN_EPS) * gp[c & (DIM2 - 1)]
                      + bp[c & (DIM2 - 1)];
            if (relu) x = fmaxf(x, 0.f);
            vv[k] = x;
        }
        ushort4 o;
        o.x = f2bf(vv[0]); o.y = f2bf(vv[1]); o.z = f2bf(vv[2]); o.w = f2bf(vv[3]);
        ((ushort4*)H16)[i] = o;
    }
}

// ---------------------------------------------------------------------------
// sampled_z = noise*exp(logstd)+mean; KL into out[3*NDTOT] (pre-zeroed).
__global__ void final_kernel(const float* __restrict__ noise, float* __restrict__ out) {
    const float* mean = out + NDTOT;
    const float* logstd = out + 2 * NDTOT;
    const int n4 = NDTOT / 4;
    float kl = 0.f;
    for (int i = blockIdx.x * blockDim.x + threadIdx.x; i < n4;
         i += gridDim.x * blockDim.x) {
        float4 m = ((const float4*)mean)[i];
        float4 ls = ((const float4*)logstd)[i];
        float4 nz = ((const float4*)noise)[i];
        float e0 = expf(ls.x), e1 = expf(ls.y), e2 = expf(ls.z), e3 = expf(ls.w);
        float4 z;
        z.x = nz.x * e0 + m.x;
        z.y = nz.y * e1 + m.y;
        z.z = nz.z * e2 + m.z;
        z.w = nz.w * e3 + m.w;
        ((float4*)out)[i] = z;
        kl += (1.f + 2.f * ls.x - m.x * m.x - e0 * e0);
        kl += (1.f + 2.f * ls.y - m.y * m.y - e1 * e1);
        kl += (1.f + 2.f * ls.z - m.z * m.z - e2 * e2);
        kl += (1.f + 2.f * ls.w - m.w * m.w - e3 * e3);
    }
    #pragma unroll
    for (int o = 32; o > 0; o >>= 1) kl += __shfl_down(kl, o);
    if ((threadIdx.x & 63) == 0) {
        const float scale = 0.5f / ((float)NNODES * (float)NNODES);
        atomicAdd(out + 3 * NDTOT, kl * scale);
    }
}

// ---------------------------------------------------------------------------
extern "C" void kernel_launch(void* const* d_in, const int* in_sizes, int n_in,
                              void* d_out, int out_size, void* d_ws, size_t ws_size,
                              hipStream_t stream) {
    const float* x     = (const float*)d_in[0];
    const int*   ei    = (const int*)d_in[1];
    const float* ea    = (const float*)d_in[2];
    const float* noise = (const float*)d_in[3];
    const float *W1[4], *b1[4], *g[4], *be[4], *W2[4], *b2[4];
    for (int i = 0; i < 4; ++i) {
        W1[i] = (const float*)d_in[4 + 6 * i];
        b1[i] = (const float*)d_in[5 + 6 * i];
        g[i]  = (const float*)d_in[6 + 6 * i];
        be[i] = (const float*)d_in[7 + 6 * i];
        W2[i] = (const float*)d_in[8 + 6 * i];
        b2[i] = (const float*)d_in[9 + 6 * i];
    }
    float* out = (float*)d_out;

    // --- workspace carve
    char* p = (char*)d_ws;
    auto carve = [&](size_t bytes) {
        char* r = p;
        p += (bytes + 255) & ~(size_t)255;
        return r;
    };
    ushort* Braw16 = (ushort*)carve((size_t)MPAD * 1024 * 2);   // GEMM1 out (<=1024 cols)
    ushort* H16    = (ushort*)carve((size_t)MPAD * DIM * 2);    // hidden bf16
    ushort* A16    = (ushort*)carve((size_t)MPAD * DIM * 2);    // agg out bf16
    ushort* WT16   = (ushort*)carve((size_t)8 * 131072 * 2);    // 8 transposed weights
    float*  stats  = (float*)carve(4096 * 4 + NNODES * 4);      // stats + cnt (one memset)
    int*    cnt    = (int*)(stats + 4096);
    int*    off    = (int*)carve((NNODES + 8) * 4);
    int*    cur    = (int*)carve(NNODES * 4);
    int*    perm_e = (int*)carve(NEDGES * 4);
    int*    perm_s = (int*)carve(NEDGES * 4);
    size_t baseBytes = (size_t)(p - (char*)d_ws);
    ushort* ea16 = (ushort*)p;
    const bool useEa16 = (baseBytes + (size_t)NEDGES * DIM * 2) <= ws_size;

    const int edgeGrid = (NEDGES + 255) / 256;
    const int aggGrid = (NNODES * 64) / 256;

    // --- weight convert + transpose (once). o[2],o[3] adjacent -> merged L23 W1.
    WPtrs wp;
    for (int i = 0; i < 4; ++i) {
        wp.w[i] = W1[i];     wp.o[i] = WT16 + (size_t)i * 131072;
        wp.K[i] = DIM;       wp.Nc[i] = DIM2;
        wp.w[4 + i] = W2[i]; wp.o[4 + i] = WT16 + (size_t)(4 + i) * 131072;
        wp.K[4 + i] = DIM2;  wp.Nc[4 + i] = DIM;
    }
    hipLaunchKernelGGL(wconv_kernel, dim3(8 * 512), dim3(256), 0, stream, wp);

    // --- zero stats + cnt in one fill; build CSR
    hipMemsetAsync(stats, 0, 4096 * 4 + NNODES * 4, stream);
    hipLaunchKernelGGL(hist_kernel, dim3(edgeGrid), dim3(256), 0, stream, ei, cnt);
    hipLaunchKernelGGL(scan_kernel, dim3(1), dim3(256), 0, stream, cnt, off, cur);
    hipLaunchKernelGGL(scatter_kernel, dim3(edgeGrid), dim3(256), 0, stream,
                       ei, cur, perm_e, perm_s);

    dim3 blk(256);
    dim3 gemm1Grid(DIM2 / 128, MPAD / 128);     // (4,157)
    dim3 gemm1WGrid(1024 / 128, MPAD / 128);    // (8,157) merged L23
    dim3 gemm2Grid(DIM / 128, MPAD / 128);      // (2,157)

    // ---------------- layer 0 ----------------
    if (useEa16)
        hipLaunchKernelGGL((agg_kernel<true, true, true>), dim3(aggGrid), blk, 0, stream,
                           x, (const ushort*)nullptr, ea, (const ushort*)nullptr, ea16,
                           off, perm_e, perm_s, A16);
    else
        hipLaunchKernelGGL((agg_kernel<true, true, false>), dim3(aggGrid), blk, 0, stream,
                           x, (const ushort*)nullptr, ea, (const ushort*)nullptr, (ushort*)nullptr,
                           off, perm_e, perm_s, A16);
    hipLaunchKernelGGL((mfma_gemm<DIM, true, true>), gemm1Grid, blk, 0, stream,
                       A16, DIM, WT16, b1[0], b1[0],
                       (float*)nullptr, Braw16, DIM2, stats, DIM2, NNODES);
    hipLaunchKernelGGL((bn_apply_kernel<DIM2>), dim3(2048), blk, 0, stream,
                       Braw16, stats, g[0], be[0], g[0], be[0], 1);
    hipLaunchKernelGGL((mfma_gemm<DIM2, true, false>), gemm2Grid, blk, 0, stream,
                       Braw16, DIM2, WT16 + 4 * 131072, b2[0], b2[0],
                       (float*)nullptr, H16, DIM, (float*)nullptr, DIM, NNODES);

    // ---------------- layer 1 ----------------
    if (useEa16)
        hipLaunchKernelGGL((agg_kernel<false, false, false>), dim3(aggGrid), blk, 0, stream,
                           (const float*)nullptr, H16, (const float*)nullptr, ea16, (ushort*)nullptr,
                           off, perm_e, perm_s, A16);
    else
        hipLaunchKernelGGL((agg_kernel<false, true, false>), dim3(aggGrid), blk, 0, stream,
                           (const float*)nullptr, H16, ea, (const ushort*)nullptr, (ushort*)nullptr,
                           off, perm_e, perm_s, A16);
    hipLaunchKernelGGL((mfma_gemm<DIM, true, true>), gemm1Grid, blk, 0, stream,
                       A16, DIM, WT16 + 1 * 131072, b1[1], b1[1],
                       (float*)nullptr, Braw16, DIM2, stats + 1024, DIM2, NNODES);
    hipLaunchKernelGGL((bn_apply_kernel<DIM2>), dim3(2048), blk, 0, stream,
                       Braw16, stats + 1024, g[1], be[1], g[1], be[1], 1);
    hipLaunchKernelGGL((mfma_gemm<DIM2, true, false>), gemm2Grid, blk, 0, stream,
                       Braw16, DIM2, WT16 + 5 * 131072, b2[1], b2[1],
                       (float*)nullptr, H16, DIM, (float*)nullptr, DIM, NNODES);

    // ---------------- layers 2+3 (merged GEMM1/BN; shared agg) ----------------
    if (useEa16)
        hipLaunchKernelGGL((agg_kernel<false, false, false>), dim3(aggGrid), blk, 0, stream,
                           (const float*)nullptr, H16, (const float*)nullptr, ea16, (ushort*)nullptr,
                           off, perm_e, perm_s, A16);
    else
        hipLaunchKernelGGL((agg_kernel<false, true, false>), dim3(aggGrid), blk, 0, stream,
                           (const float*)nullptr, H16, ea, (const ushort*)nullptr, (ushort*)nullptr,
                           off, perm_e, perm_s, A16);
    hipLaunchKernelGGL((mfma_gemm<DIM, true, true>), gemm1WGrid, blk, 0, stream,
                       A16, DIM, WT16 + 2 * 131072, b1[2], b1[3],
                       (float*)nullptr, Braw16, 1024, stats + 2048, 1024, NNODES);
    hipLaunchKernelGGL((bn_apply_kernel<1024>), dim3(2048), blk, 0, stream,
                       Braw16, stats + 2048, g[2], be[2], g[3], be[3], 0);
    hipLaunchKernelGGL((mfma_gemm<DIM2, false, false>), gemm2Grid, blk, 0, stream,
                       Braw16, 1024, WT16 + 6 * 131072, b2[2], b2[2],
                       out + NDTOT, (ushort*)nullptr, DIM, (float*)nullptr, DIM, NNODES);
    hipLaunchKernelGGL((mfma_gemm<DIM2, false, false>), gemm2Grid, blk, 0, stream,
                       Braw16 + 512, 1024, WT16 + 7 * 131072, b2[3], b2[3],
                       out + 2 * NDTOT, (ushort*)nullptr, DIM, (float*)nullptr, DIM, NNODES);

    // ---------------- final ----------------
    hipMemsetAsync(out + 3 * NDTOT, 0, sizeof(float), stream);
    hipLaunchKernelGGL(final_kernel, dim3(1280), blk, 0, stream, noise, out);
}

// Round 5
// 541.295 us; speedup vs baseline: 8.2078x; 1.1418x over previous
//
#include <hip/hip_runtime.h>

#define NNODES 20000
#define NEDGES 320000
#define DIM 256
#define DIM2 512
#define MPAD 20096          // 157 * 128
#define BN_EPS 1e-5f
#define NDTOT (NNODES * DIM)

typedef __attribute__((ext_vector_type(8))) short bf16x8;
typedef __attribute__((ext_vector_type(4))) float f32x4;

__device__ inline ushort f2bf(float f) {
    unsigned u = __float_as_uint(f);
    u += 0x7FFF + ((u >> 16) & 1);   // round-to-nearest-even
    return (ushort)(u >> 16);
}
__device__ inline float bf2f(ushort u) {
    return __uint_as_float(((unsigned)u) << 16);
}

// ---------------------------------------------------------------------------
// CSR build
__global__ void hist_kernel(const int* __restrict__ ei, int* __restrict__ cnt) {
    int e = blockIdx.x * blockDim.x + threadIdx.x;
    if (e < NEDGES) atomicAdd(&cnt[ei[NEDGES + e]], 1);
}

__global__ __launch_bounds__(256) void scan_kernel(const int* __restrict__ cnt,
                                                   int* __restrict__ off,
                                                   int* __restrict__ cur,
                                                   float* __restrict__ klP) {
    int t = threadIdx.x;
    const int CH = (NNODES + 255) / 256;
    int b0 = t * CH, b1 = min(b0 + CH, NNODES);
    int s = 0;
    for (int i = b0; i < b1; ++i) s += cnt[i];
    __shared__ int sums[256];
    sums[t] = s;
    __syncthreads();
    if (t == 0) {
        int acc = 0;
        for (int i = 0; i < 256; ++i) { int tmp = sums[i]; sums[i] = acc; acc += tmp; }
        off[NNODES] = acc;
        klP[0] = 0.f;                       // zero KL accumulator (one launch-early store)
    }
    __syncthreads();
    int run = sums[t];
    for (int i = b0; i < b1; ++i) {
        off[i] = run;
        cur[i] = run;
        run += cnt[i];
    }
}

__global__ void scatter_kernel(const int* __restrict__ ei, int* __restrict__ cur,
                               int* __restrict__ perm_e, int* __restrict__ perm_s) {
    int e = blockIdx.x * blockDim.x + threadIdx.x;
    if (e >= NEDGES) return;
    int d = ei[NEDGES + e];
    int pos = atomicAdd(&cur[d], 1);
    perm_e[pos] = e;
    perm_s[pos] = ei[e];
}

// ---------------------------------------------------------------------------
// One wave per node: A16[n] = bf16( X[n] + sum_{e->n} relu(X[src]+EA[e]) ).
// XF32: X fp32 (else bf16). EAPERM: EA is bf16 and already CSR-slot-ordered
// (index by i, no perm_e). Else EA is fp32 indexed via perm_e.
// WEA: write bf16 CSR-ordered copy of EA rows (pass 1).
template<bool XF32, bool EAPERM, bool WEA>
__global__ __launch_bounds__(256) void agg_kernel(
        const float* __restrict__ Xf, const ushort* __restrict__ Xh,
        const float* __restrict__ EAf, const ushort* __restrict__ EAh,
        ushort* __restrict__ EAout,
        const int* __restrict__ off, const int* __restrict__ perm_e,
        const int* __restrict__ perm_s, ushort* __restrict__ A16) {
    int wid = (blockIdx.x * blockDim.x + threadIdx.x) >> 6;
    if (wid >= NNODES) return;
    int l = threadIdx.x & 63;
    int s0 = off[wid], s1 = off[wid + 1];
    float4 acc;
    if (XF32) {
        acc = *(const float4*)(Xf + (size_t)wid * DIM + l * 4);
    } else {
        ushort4 v = *(const ushort4*)(Xh + (size_t)wid * DIM + l * 4);
        acc = make_float4(bf2f(v.x), bf2f(v.y), bf2f(v.z), bf2f(v.w));
    }
    #pragma unroll 2
    for (int i = s0; i < s1; ++i) {
        int s = perm_s[i];
        float4 xr, er;
        if (XF32) {
            xr = *(const float4*)(Xf + (size_t)s * DIM + l * 4);
        } else {
            ushort4 v = *(const ushort4*)(Xh + (size_t)s * DIM + l * 4);
            xr = make_float4(bf2f(v.x), bf2f(v.y), bf2f(v.z), bf2f(v.w));
        }
        if (EAPERM) {
            ushort4 v = *(const ushort4*)(EAh + (size_t)i * DIM + l * 4);
            er = make_float4(bf2f(v.x), bf2f(v.y), bf2f(v.z), bf2f(v.w));
        } else {
            int e = perm_e[i];
            er = *(const float4*)(EAf + (size_t)e * DIM + l * 4);
        }
        if (WEA) {
            ushort4 o;
            o.x = f2bf(er.x); o.y = f2bf(er.y); o.z = f2bf(er.z); o.w = f2bf(er.w);
            *(ushort4*)(EAout + (size_t)i * DIM + l * 4) = o;   // CSR slot order
        }
        acc.x += fmaxf(xr.x + er.x, 0.f);
        acc.y += fmaxf(xr.y + er.y, 0.f);
        acc.z += fmaxf(xr.z + er.z, 0.f);
        acc.w += fmaxf(xr.w + er.w, 0.f);
    }
    ushort4 o;
    o.x = f2bf(acc.x); o.y = f2bf(acc.y); o.z = f2bf(acc.z); o.w = f2bf(acc.w);
    *(ushort4*)(A16 + (size_t)wid * DIM + l * 4) = o;
}

// ---------------------------------------------------------------------------
// Weight convert+transpose: out[Nc][K] bf16 = in[K][Nc] fp32, all 8 weights.
struct WPtrs {
    const float* w[8];
    ushort* o[8];
    int K[8];
    int Nc[8];
};
__global__ __launch_bounds__(256) void wconv_kernel(WPtrs p) {
    int w = blockIdx.x >> 9;
    int idx = ((blockIdx.x & 511) << 8) + threadIdx.x;
    int K = p.K[w], Nc = p.Nc[w];
    int oc = idx / K, ok = idx - oc * K;
    p.o[w][idx] = f2bf(p.w[w][(size_t)ok * Nc + oc]);
}

// ---------------------------------------------------------------------------
// BN-fold for layers 2/3 (no ReLU): W2f[l][n][k] = bf16(sc[k]*W2T[n][k]),
// b2f[l][n] = b2[n] + sum_k (be[k]-mu[k]*sc[k])*W2T[n][k].
// stats: [0..1023]=sum, [1024..2047]=sumsq over 1024 cols (l*512+k).
__global__ __launch_bounds__(64) void wfold_kernel(
        const ushort* __restrict__ WT2_2, const ushort* __restrict__ WT2_3,
        const float* __restrict__ stats,
        const float* __restrict__ g2, const float* __restrict__ be2,
        const float* __restrict__ g3, const float* __restrict__ be3,
        const float* __restrict__ b2_2, const float* __restrict__ b2_3,
        ushort* __restrict__ W2f, float* __restrict__ b2f) {
    const int l = blockIdx.x >> 8;          // layer sel (0->conv2, 1->conv3)
    const int n = blockIdx.x & 255;
    const int lane = threadIdx.x;
    const float invN = 1.0f / (float)NNODES;
    const ushort* WT = l ? WT2_3 : WT2_2;
    const float* gp = l ? g3 : g2;
    const float* bp = l ? be3 : be2;
    float part = 0.f;
    #pragma unroll
    for (int j = 0; j < 8; ++j) {
        int k = j * 64 + lane;
        int c = l * DIM2 + k;
        float mu = stats[c] * invN;
        float var = stats[1024 + c] * invN - mu * mu;
        float sc = gp[k] * rsqrtf(var + BN_EPS);
        float sh = bp[k] - mu * sc;
        float wv = bf2f(WT[(size_t)n * DIM2 + k]);
        W2f[(size_t)l * 131072 + (size_t)n * DIM2 + k] = f2bf(sc * wv);
        part += sh * wv;
    }
    #pragma unroll
    for (int o = 32; o > 0; o >>= 1) part += __shfl_down(part, o);
    if (lane == 0) b2f[l * 256 + n] = (l ? b2_3[n] : b2_2[n]) + part;
}

// ---------------------------------------------------------------------------
// MFMA GEMM: out[gr][gc] = sum_k A16[gr][k]*WT[gc][k] + bias[gc]
// Block 128x128, BK=64, 4 waves (2x2), 64x64/wave.
// STATS: per-column sum/sumsq into stats (pre-zeroed). bias2 for gc>=512.
// FINAL: treat output as logstd; also read mean/noise, write z and KL.
template<int K, bool OUT_BF16, bool STATS, bool FINAL>
__global__ __launch_bounds__(256) void mfma_gemm(
        const ushort* __restrict__ A16, int lda,
        const ushort* __restrict__ WT,
        const float* __restrict__ bias, const float* __restrict__ bias2,
        float* __restrict__ Cf, ushort* __restrict__ C16, int ldc,
        float* __restrict__ stats, int Nc, int Mlimit,
        const float* __restrict__ meanP, const float* __restrict__ noiseP,
        float* __restrict__ zP, float* __restrict__ klP) {
    __shared__ ushort As[128 * 72];
    __shared__ ushort Bs[128 * 72];
    const int tid = threadIdx.x;
    const int lane = tid & 63;
    const int wv = tid >> 6, wr = wv >> 1, wc = wv & 1;
    const int l15 = lane & 15, lhi = lane >> 4;
    const int r0 = blockIdx.y * 128, c0 = blockIdx.x * 128;
    const int srow = tid >> 1;
    const int sseg = (tid & 1) * 4;

    f32x4 acc[4][4] = {};

    for (int k0 = 0; k0 < K; k0 += 64) {
        const ushort* ga = A16 + (size_t)(r0 + srow) * lda + k0 + sseg * 8;
        const ushort* gb = WT + (size_t)(c0 + srow) * K + k0 + sseg * 8;
        ushort* la = As + srow * 72 + sseg * 8;
        ushort* lb = Bs + srow * 72 + sseg * 8;
        #pragma unroll
        for (int i = 0; i < 4; ++i) {
            *(uint4*)(la + i * 8) = *(const uint4*)(ga + i * 8);
            *(uint4*)(lb + i * 8) = *(const uint4*)(gb + i * 8);
        }
        __syncthreads();
        #pragma unroll
        for (int kk = 0; kk < 2; ++kk) {
            bf16x8 a[4], b[4];
            #pragma unroll
            for (int m = 0; m < 4; ++m)
                a[m] = *(const bf16x8*)(As + (wr * 64 + m * 16 + l15) * 72 + kk * 32 + lhi * 8);
            #pragma unroll
            for (int n = 0; n < 4; ++n)
                b[n] = *(const bf16x8*)(Bs + (wc * 64 + n * 16 + l15) * 72 + kk * 32 + lhi * 8);
            #pragma unroll
            for (int m = 0; m < 4; ++m)
                #pragma unroll
                for (int n = 0; n < 4; ++n)
                    acc[m][n] = __builtin_amdgcn_mfma_f32_16x16x32_bf16(
                        a[m], b[n], acc[m][n], 0, 0, 0);
        }
        __syncthreads();
    }

    float bv[4];
    #pragma unroll
    for (int n = 0; n < 4; ++n) {
        int gc = c0 + wc * 64 + n * 16 + l15;
        bv[n] = (gc < DIM2) ? bias[gc] : bias2[gc - DIM2];
    }
    float sm[4] = {0.f, 0.f, 0.f, 0.f}, sq[4] = {0.f, 0.f, 0.f, 0.f};
    float kl = 0.f;
    #pragma unroll
    for (int m = 0; m < 4; ++m) {
        #pragma unroll
        for (int q = 0; q < 4; ++q) {
            int gr = r0 + wr * 64 + m * 16 + lhi * 4 + q;
            if (gr >= Mlimit) continue;
            #pragma unroll
            for (int n = 0; n < 4; ++n) {
                int gc = c0 + wc * 64 + n * 16 + l15;
                float v = acc[m][n][q] + bv[n];
                if (OUT_BF16) C16[(size_t)gr * ldc + gc] = f2bf(v);
                else          Cf[(size_t)gr * ldc + gc] = v;
                if (STATS) { sm[n] += v; sq[n] += v * v; }
                if (FINAL) {
                    size_t idx = (size_t)gr * DIM + gc;
                    float mean = meanP[idx];
                    float nz = noiseP[idx];
                    float e = expf(v);
                    zP[idx] = nz * e + mean;
                    kl += 1.f + 2.f * v - mean * mean - e * e;
                }
            }
        }
    }
    if (STATS) {
        #pragma unroll
        for (int n = 0; n < 4; ++n) {
            float sv = sm[n], qv = sq[n];
            sv += __shfl_xor(sv, 16); sv += __shfl_xor(sv, 32);
            qv += __shfl_xor(qv, 16); qv += __shfl_xor(qv, 32);
            if (lane < 16) {
                int gc = c0 + wc * 64 + n * 16 + l15;
                atomicAdd(&stats[gc], sv);
                atomicAdd(&stats[Nc + gc], qv);
            }
        }
    }
    if (FINAL) {
        #pragma unroll
        for (int o = 32; o > 0; o >>= 1) kl += __shfl_down(kl, o);
        if (lane == 0) {
            const float scale = 0.5f / ((float)NNODES * (float)NNODES);
            atomicAdd(klP, kl * scale);
        }
    }
}

// ---------------------------------------------------------------------------
// BN apply in-place on bf16 [NNODES, NCOLS] (layers 0/1, ReLU).
template<int NCOLS>
__global__ __launch_bounds__(256) void bn_apply_kernel(
        ushort* __restrict__ H16, const float* __restrict__ stats,
        const float* __restrict__ g0, const float* __restrict__ be0) {
    const float invN = 1.0f / (float)NNODES;
    const int n4 = NNODES * NCOLS / 4;
    for (int i = blockIdx.x * blockDim.x + threadIdx.x; i < n4;
         i += gridDim.x * blockDim.x) {
        int cbase = (i * 4) & (NCOLS - 1);
        ushort4 u = ((const ushort4*)H16)[i];
        float vv[4] = {bf2f(u.x), bf2f(u.y), bf2f(u.z), bf2f(u.w)};
        #pragma unroll
        for (int k = 0; k < 4; ++k) {
            int c = cbase + k;
            float mu = stats[c] * invN;
            float var = stats[NCOLS + c] * invN - mu * mu;
            float x = (vv[k] - mu) * rsqrtf(var + BN_EPS) * g0[c] + be0[c];
            vv[k] = fmaxf(x, 0.f);
        }
        ushort4 o;
        o.x = f2bf(vv[0]); o.y = f2bf(vv[1]); o.z = f2bf(vv[2]); o.w = f2bf(vv[3]);
        ((ushort4*)H16)[i] = o;
    }
}

// ---------------------------------------------------------------------------
extern "C" void kernel_launch(void* const* d_in, const int* in_sizes, int n_in,
                              void* d_out, int out_size, void* d_ws, size_t ws_size,
                              hipStream_t stream) {
    const float* x     = (const float*)d_in[0];
    const int*   ei    = (const int*)d_in[1];
    const float* ea    = (const float*)d_in[2];
    const float* noise = (const float*)d_in[3];
    const float *W1[4], *b1[4], *g[4], *be[4], *W2[4], *b2[4];
    for (int i = 0; i < 4; ++i) {
        W1[i] = (const float*)d_in[4 + 6 * i];
        b1[i] = (const float*)d_in[5 + 6 * i];
        g[i]  = (const float*)d_in[6 + 6 * i];
        be[i] = (const float*)d_in[7 + 6 * i];
        W2[i] = (const float*)d_in[8 + 6 * i];
        b2[i] = (const float*)d_in[9 + 6 * i];
    }
    float* out = (float*)d_out;
    float* klP = out + 3 * NDTOT;

    // --- workspace carve
    char* p = (char*)d_ws;
    auto carve = [&](size_t bytes) {
        char* r = p;
        p += (bytes + 255) & ~(size_t)255;
        return r;
    };
    ushort* Braw16 = (ushort*)carve((size_t)MPAD * 1024 * 2);   // GEMM1 out (<=1024 cols)
    ushort* H16    = (ushort*)carve((size_t)MPAD * DIM * 2);    // hidden bf16
    ushort* A16    = (ushort*)carve((size_t)MPAD * DIM * 2);    // agg out bf16
    ushort* WT16   = (ushort*)carve((size_t)8 * 131072 * 2);    // 8 transposed weights
    ushort* W2f    = (ushort*)carve((size_t)2 * 131072 * 2);    // folded L23 weights
    float*  b2f    = (float*)carve(512 * 4);                    // folded L23 biases
    float*  stats  = (float*)carve(4096 * 4 + NNODES * 4);      // stats + cnt (one memset)
    int*    cnt    = (int*)(stats + 4096);
    int*    off    = (int*)carve((NNODES + 8) * 4);
    int*    cur    = (int*)carve(NNODES * 4);
    int*    perm_e = (int*)carve(NEDGES * 4);
    int*    perm_s = (int*)carve(NEDGES * 4);
    size_t baseBytes = (size_t)(p - (char*)d_ws);
    ushort* ea16 = (ushort*)p;
    const bool useEa16 = (baseBytes + (size_t)NEDGES * DIM * 2) <= ws_size;

    const int edgeGrid = (NEDGES + 255) / 256;
    const int aggGrid = (NNODES * 64) / 256;

    // --- weight convert + transpose (once). o[2],o[3] adjacent -> merged L23 W1.
    WPtrs wp;
    for (int i = 0; i < 4; ++i) {
        wp.w[i] = W1[i];     wp.o[i] = WT16 + (size_t)i * 131072;
        wp.K[i] = DIM;       wp.Nc[i] = DIM2;
        wp.w[4 + i] = W2[i]; wp.o[4 + i] = WT16 + (size_t)(4 + i) * 131072;
        wp.K[4 + i] = DIM2;  wp.Nc[4 + i] = DIM;
    }
    hipLaunchKernelGGL(wconv_kernel, dim3(8 * 512), dim3(256), 0, stream, wp);

    // --- zero stats + cnt in one fill; build CSR (scan also zeroes KL)
    hipMemsetAsync(stats, 0, 4096 * 4 + NNODES * 4, stream);
    hipLaunchKernelGGL(hist_kernel, dim3(edgeGrid), dim3(256), 0, stream, ei, cnt);
    hipLaunchKernelGGL(scan_kernel, dim3(1), dim3(256), 0, stream, cnt, off, cur, klP);
    hipLaunchKernelGGL(scatter_kernel, dim3(edgeGrid), dim3(256), 0, stream,
                       ei, cur, perm_e, perm_s);

    dim3 blk(256);
    dim3 gemm1Grid(DIM2 / 128, MPAD / 128);     // (4,157)
    dim3 gemm1WGrid(1024 / 128, MPAD / 128);    // (8,157) merged L23
    dim3 gemm2Grid(DIM / 128, MPAD / 128);      // (2,157)
    const float* nf = nullptr;
    float* nfm = nullptr;

    // ---------------- layer 0 ----------------
    if (useEa16)
        hipLaunchKernelGGL((agg_kernel<true, false, true>), dim3(aggGrid), blk, 0, stream,
                           x, (const ushort*)nullptr, ea, (const ushort*)nullptr, ea16,
                           off, perm_e, perm_s, A16);
    else
        hipLaunchKernelGGL((agg_kernel<true, false, false>), dim3(aggGrid), blk, 0, stream,
                           x, (const ushort*)nullptr, ea, (const ushort*)nullptr, (ushort*)nullptr,
                           off, perm_e, perm_s, A16);
    hipLaunchKernelGGL((mfma_gemm<DIM, true, true, false>), gemm1Grid, blk, 0, stream,
                       A16, DIM, WT16, b1[0], b1[0],
                       nfm, Braw16, DIM2, stats, DIM2, NNODES, nf, nf, nfm, nfm);
    hipLaunchKernelGGL((bn_apply_kernel<DIM2>), dim3(2048), blk, 0, stream,
                       Braw16, stats, g[0], be[0]);
    hipLaunchKernelGGL((mfma_gemm<DIM2, true, false, false>), gemm2Grid, blk, 0, stream,
                       Braw16, DIM2, WT16 + 4 * 131072, b2[0], b2[0],
                       nfm, H16, DIM, nfm, DIM, NNODES, nf, nf, nfm, nfm);

    // ---------------- layer 1 ----------------
    if (useEa16)
        hipLaunchKernelGGL((agg_kernel<false, true, false>), dim3(aggGrid), blk, 0, stream,
                           (const float*)nullptr, H16, (const float*)nullptr, ea16, (ushort*)nullptr,
                           off, perm_e, perm_s, A16);
    else
        hipLaunchKernelGGL((agg_kernel<false, false, false>), dim3(aggGrid), blk, 0, stream,
                           (const float*)nullptr, H16, ea, (const ushort*)nullptr, (ushort*)nullptr,
                           off, perm_e, perm_s, A16);
    hipLaunchKernelGGL((mfma_gemm<DIM, true, true, false>), gemm1Grid, blk, 0, stream,
                       A16, DIM, WT16 + 1 * 131072, b1[1], b1[1],
                       nfm, Braw16, DIM2, stats + 1024, DIM2, NNODES, nf, nf, nfm, nfm);
    hipLaunchKernelGGL((bn_apply_kernel<DIM2>), dim3(2048), blk, 0, stream,
                       Braw16, stats + 1024, g[1], be[1]);
    hipLaunchKernelGGL((mfma_gemm<DIM2, true, false, false>), gemm2Grid, blk, 0, stream,
                       Braw16, DIM2, WT16 + 5 * 131072, b2[1], b2[1],
                       nfm, H16, DIM, nfm, DIM, NNODES, nf, nf, nfm, nfm);

    // ---------------- layers 2+3 (merged GEMM1; BN folded into GEMM2) --------
    if (useEa16)
        hipLaunchKernelGGL((agg_kernel<false, true, false>), dim3(aggGrid), blk, 0, stream,
                           (const float*)nullptr, H16, (const float*)nullptr, ea16, (ushort*)nullptr,
                           off, perm_e, perm_s, A16);
    else
        hipLaunchKernelGGL((agg_kernel<false, false, false>), dim3(aggGrid), blk, 0, stream,
                           (const float*)nullptr, H16, ea, (const ushort*)nullptr, (ushort*)nullptr,
                           off, perm_e, perm_s, A16);
    hipLaunchKernelGGL((mfma_gemm<DIM, true, true, false>), gemm1WGrid, blk, 0, stream,
                       A16, DIM, WT16 + 2 * 131072, b1[2], b1[3],
                       nfm, Braw16, 1024, stats + 2048, 1024, NNODES, nf, nf, nfm, nfm);
    hipLaunchKernelGGL(wfold_kernel, dim3(512), dim3(64), 0, stream,
                       WT16 + 6 * 131072, WT16 + 7 * 131072, stats + 2048,
                       g[2], be[2], g[3], be[3], b2[2], b2[3], W2f, b2f);
    // mean = Braw16[:,0:512] @ W2f_0 + b2f_0
    hipLaunchKernelGGL((mfma_gemm<DIM2, false, false, false>), gemm2Grid, blk, 0, stream,
                       Braw16, 1024, W2f, b2f, b2f,
                       out + NDTOT, (ushort*)nullptr, DIM, nfm, DIM, NNODES, nf, nf, nfm, nfm);
    // logstd = Braw16[:,512:1024] @ W2f_1 + b2f_1 ; fused z + KL
    hipLaunchKernelGGL((mfma_gemm<DIM2, false, false, true>), gemm2Grid, blk, 0, stream,
                       Braw16 + 512, 1024, W2f + 131072, b2f + 256, b2f + 256,
                       out + 2 * NDTOT, (ushort*)nullptr, DIM, nfm, DIM, NNODES,
                       out + NDTOT, noise, out, klP);
}

// Round 6
// 517.142 us; speedup vs baseline: 8.5911x; 1.0467x over previous
//
#include <hip/hip_runtime.h>

#define NNODES 20000
#define NEDGES 320000
#define DIM 256
#define DIM2 512
#define MPAD 20096          // 157 * 128
#define BN_EPS 1e-5f
#define NDTOT (NNODES * DIM)

typedef __attribute__((ext_vector_type(8))) short bf16x8;
typedef __attribute__((ext_vector_type(4))) float f32x4;

typedef __attribute__((address_space(1))) const unsigned char gconst_byte;
typedef __attribute__((address_space(3))) unsigned char lds_byte;

__device__ inline ushort f2bf(float f) {
    unsigned u = __float_as_uint(f);
    u += 0x7FFF + ((u >> 16) & 1);   // round-to-nearest-even
    return (ushort)(u >> 16);
}
__device__ inline float bf2f(ushort u) {
    return __uint_as_float(((unsigned)u) << 16);
}

// ---------------------------------------------------------------------------
// CSR build
__global__ void hist_kernel(const int* __restrict__ ei, int* __restrict__ cnt) {
    int e = blockIdx.x * blockDim.x + threadIdx.x;
    if (e < NEDGES) atomicAdd(&cnt[ei[NEDGES + e]], 1);
}

__global__ __launch_bounds__(256) void scan_kernel(const int* __restrict__ cnt,
                                                   int* __restrict__ off,
                                                   int* __restrict__ cur,
                                                   float* __restrict__ klP) {
    int t = threadIdx.x;
    const int CH = (NNODES + 255) / 256;
    int b0 = t * CH, b1 = min(b0 + CH, NNODES);
    int s = 0;
    for (int i = b0; i < b1; ++i) s += cnt[i];
    __shared__ int sums[256];
    sums[t] = s;
    __syncthreads();
    if (t == 0) {
        int acc = 0;
        for (int i = 0; i < 256; ++i) { int tmp = sums[i]; sums[i] = acc; acc += tmp; }
        off[NNODES] = acc;
        klP[0] = 0.f;                       // zero KL accumulator
    }
    __syncthreads();
    int run = sums[t];
    for (int i = b0; i < b1; ++i) {
        off[i] = run;
        cur[i] = run;
        run += cnt[i];
    }
}

__global__ void scatter_kernel(const int* __restrict__ ei, int* __restrict__ cur,
                               int* __restrict__ perm_e, int* __restrict__ perm_s) {
    int e = blockIdx.x * blockDim.x + threadIdx.x;
    if (e >= NEDGES) return;
    int d = ei[NEDGES + e];
    int pos = atomicAdd(&cur[d], 1);
    perm_e[pos] = e;
    perm_s[pos] = ei[e];
}

// ---------------------------------------------------------------------------
// One wave per node: A16[n] = bf16( X[n] + sum_{e->n} relu(X[src]+EA[e]) ).
// XF32: X fp32 (else bf16). EAPERM: EA bf16, CSR-slot-ordered (index i).
// WEA: write bf16 CSR-ordered copy of EA rows (pass 1).
template<bool XF32, bool EAPERM, bool WEA>
__global__ __launch_bounds__(256) void agg_kernel(
        const float* __restrict__ Xf, const ushort* __restrict__ Xh,
        const float* __restrict__ EAf, const ushort* __restrict__ EAh,
        ushort* __restrict__ EAout,
        const int* __restrict__ off, const int* __restrict__ perm_e,
        const int* __restrict__ perm_s, ushort* __restrict__ A16) {
    int wid = (blockIdx.x * blockDim.x + threadIdx.x) >> 6;
    if (wid >= NNODES) return;
    int l = threadIdx.x & 63;
    int s0 = off[wid], s1 = off[wid + 1];
    float4 acc;
    if (XF32) {
        acc = *(const float4*)(Xf + (size_t)wid * DIM + l * 4);
    } else {
        ushort4 v = *(const ushort4*)(Xh + (size_t)wid * DIM + l * 4);
        acc = make_float4(bf2f(v.x), bf2f(v.y), bf2f(v.z), bf2f(v.w));
    }
    #pragma unroll 2
    for (int i = s0; i < s1; ++i) {
        int s = perm_s[i];
        float4 xr, er;
        if (XF32) {
            xr = *(const float4*)(Xf + (size_t)s * DIM + l * 4);
        } else {
            ushort4 v = *(const ushort4*)(Xh + (size_t)s * DIM + l * 4);
            xr = make_float4(bf2f(v.x), bf2f(v.y), bf2f(v.z), bf2f(v.w));
        }
        if (EAPERM) {
            ushort4 v = *(const ushort4*)(EAh + (size_t)i * DIM + l * 4);
            er = make_float4(bf2f(v.x), bf2f(v.y), bf2f(v.z), bf2f(v.w));
        } else {
            int e = perm_e[i];
            er = *(const float4*)(EAf + (size_t)e * DIM + l * 4);
        }
        if (WEA) {
            ushort4 o;
            o.x = f2bf(er.x); o.y = f2bf(er.y); o.z = f2bf(er.z); o.w = f2bf(er.w);
            *(ushort4*)(EAout + (size_t)i * DIM + l * 4) = o;   // CSR slot order
        }
        acc.x += fmaxf(xr.x + er.x, 0.f);
        acc.y += fmaxf(xr.y + er.y, 0.f);
        acc.z += fmaxf(xr.z + er.z, 0.f);
        acc.w += fmaxf(xr.w + er.w, 0.f);
    }
    ushort4 o;
    o.x = f2bf(acc.x); o.y = f2bf(acc.y); o.z = f2bf(acc.z); o.w = f2bf(acc.w);
    *(ushort4*)(A16 + (size_t)wid * DIM + l * 4) = o;
}

// ---------------------------------------------------------------------------
// Weight convert+transpose: out[Nc][K] bf16 = in[K][Nc] fp32, all 8 weights.
struct WPtrs {
    const float* w[8];
    ushort* o[8];
    int K[8];
    int Nc[8];
};
__global__ __launch_bounds__(256) void wconv_kernel(WPtrs p) {
    int w = blockIdx.x >> 9;
    int idx = ((blockIdx.x & 511) << 8) + threadIdx.x;
    int K = p.K[w], Nc = p.Nc[w];
    int oc = idx / K, ok = idx - oc * K;
    p.o[w][idx] = f2bf(p.w[w][(size_t)ok * Nc + oc]);
}

// ---------------------------------------------------------------------------
// BN-fold for layers 2/3 (no ReLU): W2f[l][n][k] = bf16(sc[k]*W2T[n][k]),
// b2f[l][n] = b2[n] + sum_k (be[k]-mu[k]*sc[k])*W2T[n][k].
__global__ __launch_bounds__(64) void wfold_kernel(
        const ushort* __restrict__ WT2_2, const ushort* __restrict__ WT2_3,
        const float* __restrict__ stats,
        const float* __restrict__ g2, const float* __restrict__ be2,
        const float* __restrict__ g3, const float* __restrict__ be3,
        const float* __restrict__ b2_2, const float* __restrict__ b2_3,
        ushort* __restrict__ W2f, float* __restrict__ b2f) {
    const int l = blockIdx.x >> 8;          // layer sel (0->conv2, 1->conv3)
    const int n = blockIdx.x & 255;
    const int lane = threadIdx.x;
    const float invN = 1.0f / (float)NNODES;
    const ushort* WT = l ? WT2_3 : WT2_2;
    const float* gp = l ? g3 : g2;
    const float* bp = l ? be3 : be2;
    float part = 0.f;
    #pragma unroll
    for (int j = 0; j < 8; ++j) {
        int k = j * 64 + lane;
        int c = l * DIM2 + k;
        float mu = stats[c] * invN;
        float var = stats[1024 + c] * invN - mu * mu;
        float sc = gp[k] * rsqrtf(var + BN_EPS);
        float sh = bp[k] - mu * sc;
        float wv = bf2f(WT[(size_t)n * DIM2 + k]);
        W2f[(size_t)l * 131072 + (size_t)n * DIM2 + k] = f2bf(sc * wv);
        part += sh * wv;
    }
    #pragma unroll
    for (int o = 32; o > 0; o >>= 1) part += __shfl_down(part, o);
    if (lane == 0) b2f[l * 256 + n] = (l ? b2_3[n] : b2_2[n]) + part;
}

// ---------------------------------------------------------------------------
// MFMA GEMM: out[gr][gc] = sum_k A16[gr][k]*WT[gc][k] + bias[gc]
// Block 128x128, BK=64, 4 waves (2x2), 64x64/wave.
// Staging: global_load_lds width=16, linear LDS [128][64] bf16, both-sides
// XOR swizzle byte' = byte ^ ((row&7)<<4) (inverse-swizzled global source,
// swizzled ds_read addresses) -- rule #21 compliant.
// STATS: per-column sum/sumsq into stats (pre-zeroed). bias2 for gc>=512.
// FINAL: output=logstd; read mean/noise, write z and KL.
template<int K, bool OUT_BF16, bool STATS, bool FINAL>
__global__ __launch_bounds__(256) void mfma_gemm(
        const ushort* __restrict__ A16, int lda,
        const ushort* __restrict__ WT,
        const float* __restrict__ bias, const float* __restrict__ bias2,
        float* __restrict__ Cf, ushort* __restrict__ C16, int ldc,
        float* __restrict__ stats, int Nc, int Mlimit,
        const float* __restrict__ meanP, const float* __restrict__ noiseP,
        float* __restrict__ zP, float* __restrict__ klP) {
    __shared__ ushort As[128 * 64];
    __shared__ ushort Bs[128 * 64];
    const int tid = threadIdx.x;
    const int lane = tid & 63;
    const int wv = tid >> 6, wr = wv >> 1, wc = wv & 1;
    const int l15 = lane & 15, lhi = lane >> 4;
    const int r0 = blockIdx.y * 128, c0 = blockIdx.x * 128;

    // staging geometry: issue j of wave wv covers rows jp*8..jp*8+7 (jp=j*4+wv),
    // LDS bytes jp*1024 + lane*16 (linear). Inverse-swizzled source column.
    const int srow = lane >> 3;                       // 0..7
    const int scol = ((lane & 7) ^ srow) * 8;         // element offset in K-slab
    const int smask = (l15 & 7) << 4;                 // read-side swizzle mask

    f32x4 acc[4][4] = {};

    for (int k0 = 0; k0 < K; k0 += 64) {
        #pragma unroll
        for (int j = 0; j < 4; ++j) {
            const int jp = j * 4 + wv;
            const ushort* ga = A16 + (size_t)(r0 + jp * 8 + srow) * lda + k0 + scol;
            const ushort* gb = WT + (size_t)(c0 + jp * 8 + srow) * K + k0 + scol;
            __builtin_amdgcn_global_load_lds(
                (gconst_byte*)ga, (lds_byte*)((char*)As + jp * 1024), 16, 0, 0);
            __builtin_amdgcn_global_load_lds(
                (gconst_byte*)gb, (lds_byte*)((char*)Bs + jp * 1024), 16, 0, 0);
        }
        __syncthreads();
        #pragma unroll
        for (int kk = 0; kk < 2; ++kk) {
            bf16x8 a[4], b[4];
            #pragma unroll
            for (int m = 0; m < 4; ++m)
                a[m] = *(const bf16x8*)((const char*)As +
                        (wr * 64 + m * 16 + l15) * 128 + ((kk * 64 + lhi * 16) ^ smask));
            #pragma unroll
            for (int n = 0; n < 4; ++n)
                b[n] = *(const bf16x8*)((const char*)Bs +
                        (wc * 64 + n * 16 + l15) * 128 + ((kk * 64 + lhi * 16) ^ smask));
            #pragma unroll
            for (int m = 0; m < 4; ++m)
                #pragma unroll
                for (int n = 0; n < 4; ++n)
                    acc[m][n] = __builtin_amdgcn_mfma_f32_16x16x32_bf16(
                        a[m], b[n], acc[m][n], 0, 0, 0);
        }
        __syncthreads();
    }

    float bv[4];
    #pragma unroll
    for (int n = 0; n < 4; ++n) {
        int gc = c0 + wc * 64 + n * 16 + l15;
        bv[n] = (gc < DIM2) ? bias[gc] : bias2[gc - DIM2];
    }
    float sm[4] = {0.f, 0.f, 0.f, 0.f}, sq[4] = {0.f, 0.f, 0.f, 0.f};
    float kl = 0.f;
    #pragma unroll
    for (int m = 0; m < 4; ++m) {
        #pragma unroll
        for (int q = 0; q < 4; ++q) {
            int gr = r0 + wr * 64 + m * 16 + lhi * 4 + q;
            if (gr >= Mlimit) continue;
            #pragma unroll
            for (int n = 0; n < 4; ++n) {
                int gc = c0 + wc * 64 + n * 16 + l15;
                float v = acc[m][n][q] + bv[n];
                if (OUT_BF16) C16[(size_t)gr * ldc + gc] = f2bf(v);
                else          Cf[(size_t)gr * ldc + gc] = v;
                if (STATS) { sm[n] += v; sq[n] += v * v; }
                if (FINAL) {
                    size_t idx = (size_t)gr * DIM + gc;
                    float mean = meanP[idx];
                    float nz = noiseP[idx];
                    float e = expf(v);
                    zP[idx] = nz * e + mean;
                    kl += 1.f + 2.f * v - mean * mean - e * e;
                }
            }
        }
    }
    if (STATS) {
        #pragma unroll
        for (int n = 0; n < 4; ++n) {
            float sv = sm[n], qv = sq[n];
            sv += __shfl_xor(sv, 16); sv += __shfl_xor(sv, 32);
            qv += __shfl_xor(qv, 16); qv += __shfl_xor(qv, 32);
            if (lane < 16) {
                int gc = c0 + wc * 64 + n * 16 + l15;
                atomicAdd(&stats[gc], sv);
                atomicAdd(&stats[Nc + gc], qv);
            }
        }
    }
    if (FINAL) {
        #pragma unroll
        for (int o = 32; o > 0; o >>= 1) kl += __shfl_down(kl, o);
        if (lane == 0) {
            const float scale = 0.5f / ((float)NNODES * (float)NNODES);
            atomicAdd(klP, kl * scale);
        }
    }
}

// ---------------------------------------------------------------------------
// BN apply in-place on bf16 [NNODES, NCOLS] (layers 0/1, ReLU).
template<int NCOLS>
__global__ __launch_bounds__(256) void bn_apply_kernel(
        ushort* __restrict__ H16, const float* __restrict__ stats,
        const float* __restrict__ g0, const float* __restrict__ be0) {
    const float invN = 1.0f / (float)NNODES;
    const int n4 = NNODES * NCOLS / 4;
    for (int i = blockIdx.x * blockDim.x + threadIdx.x; i < n4;
         i += gridDim.x * blockDim.x) {
        int cbase = (i * 4) & (NCOLS - 1);
        ushort4 u = ((const ushort4*)H16)[i];
        float vv[4] = {bf2f(u.x), bf2f(u.y), bf2f(u.z), bf2f(u.w)};
        #pragma unroll
        for (int k = 0; k < 4; ++k) {
            int c = cbase + k;
            float mu = stats[c] * invN;
            float var = stats[NCOLS + c] * invN - mu * mu;
            float x = (vv[k] - mu) * rsqrtf(var + BN_EPS) * g0[c] + be0[c];
            vv[k] = fmaxf(x, 0.f);
        }
        ushort4 o;
        o.x = f2bf(vv[0]); o.y = f2bf(vv[1]); o.z = f2bf(vv[2]); o.w = f2bf(vv[3]);
        ((ushort4*)H16)[i] = o;
    }
}

// ---------------------------------------------------------------------------
extern "C" void kernel_launch(void* const* d_in, const int* in_sizes, int n_in,
                              void* d_out, int out_size, void* d_ws, size_t ws_size,
                              hipStream_t stream) {
    const float* x     = (const float*)d_in[0];
    const int*   ei    = (const int*)d_in[1];
    const float* ea    = (const float*)d_in[2];
    const float* noise = (const float*)d_in[3];
    const float *W1[4], *b1[4], *g[4], *be[4], *W2[4], *b2[4];
    for (int i = 0; i < 4; ++i) {
        W1[i] = (const float*)d_in[4 + 6 * i];
        b1[i] = (const float*)d_in[5 + 6 * i];
        g[i]  = (const float*)d_in[6 + 6 * i];
        be[i] = (const float*)d_in[7 + 6 * i];
        W2[i] = (const float*)d_in[8 + 6 * i];
        b2[i] = (const float*)d_in[9 + 6 * i];
    }
    float* out = (float*)d_out;
    float* klP = out + 3 * NDTOT;

    // --- workspace carve
    char* p = (char*)d_ws;
    auto carve = [&](size_t bytes) {
        char* r = p;
        p += (bytes + 255) & ~(size_t)255;
        return r;
    };
    ushort* Braw16 = (ushort*)carve((size_t)MPAD * 1024 * 2);   // GEMM1 out (<=1024 cols)
    ushort* H16    = (ushort*)carve((size_t)MPAD * DIM * 2);    // hidden bf16
    ushort* A16    = (ushort*)carve((size_t)MPAD * DIM * 2);    // agg out bf16
    ushort* WT16   = (ushort*)carve((size_t)8 * 131072 * 2);    // 8 transposed weights
    ushort* W2f    = (ushort*)carve((size_t)2 * 131072 * 2);    // folded L23 weights
    float*  b2f    = (float*)carve(512 * 4);                    // folded L23 biases
    float*  stats  = (float*)carve(4096 * 4 + NNODES * 4);      // stats + cnt (one memset)
    int*    cnt    = (int*)(stats + 4096);
    int*    off    = (int*)carve((NNODES + 8) * 4);
    int*    cur    = (int*)carve(NNODES * 4);
    int*    perm_e = (int*)carve(NEDGES * 4);
    int*    perm_s = (int*)carve(NEDGES * 4);
    size_t baseBytes = (size_t)(p - (char*)d_ws);
    ushort* ea16 = (ushort*)p;
    const bool useEa16 = (baseBytes + (size_t)NEDGES * DIM * 2) <= ws_size;

    const int edgeGrid = (NEDGES + 255) / 256;
    const int aggGrid = (NNODES * 64) / 256;

    // --- weight convert + transpose (once). o[2],o[3] adjacent -> merged L23 W1.
    WPtrs wp;
    for (int i = 0; i < 4; ++i) {
        wp.w[i] = W1[i];     wp.o[i] = WT16 + (size_t)i * 131072;
        wp.K[i] = DIM;       wp.Nc[i] = DIM2;
        wp.w[4 + i] = W2[i]; wp.o[4 + i] = WT16 + (size_t)(4 + i) * 131072;
        wp.K[4 + i] = DIM2;  wp.Nc[4 + i] = DIM;
    }
    hipLaunchKernelGGL(wconv_kernel, dim3(8 * 512), dim3(256), 0, stream, wp);

    // --- zero stats + cnt in one fill; build CSR (scan also zeroes KL)
    hipMemsetAsync(stats, 0, 4096 * 4 + NNODES * 4, stream);
    hipLaunchKernelGGL(hist_kernel, dim3(edgeGrid), dim3(256), 0, stream, ei, cnt);
    hipLaunchKernelGGL(scan_kernel, dim3(1), dim3(256), 0, stream, cnt, off, cur, klP);
    hipLaunchKernelGGL(scatter_kernel, dim3(edgeGrid), dim3(256), 0, stream,
                       ei, cur, perm_e, perm_s);

    dim3 blk(256);
    dim3 gemm1Grid(DIM2 / 128, MPAD / 128);     // (4,157)
    dim3 gemm1WGrid(1024 / 128, MPAD / 128);    // (8,157) merged L23
    dim3 gemm2Grid(DIM / 128, MPAD / 128);      // (2,157)
    const float* nf = nullptr;
    float* nfm = nullptr;

    // ---------------- layer 0 ----------------
    if (useEa16)
        hipLaunchKernelGGL((agg_kernel<true, false, true>), dim3(aggGrid), blk, 0, stream,
                           x, (const ushort*)nullptr, ea, (const ushort*)nullptr, ea16,
                           off, perm_e, perm_s, A16);
    else
        hipLaunchKernelGGL((agg_kernel<true, false, false>), dim3(aggGrid), blk, 0, stream,
                           x, (const ushort*)nullptr, ea, (const ushort*)nullptr, (ushort*)nullptr,
                           off, perm_e, perm_s, A16);
    hipLaunchKernelGGL((mfma_gemm<DIM, true, true, false>), gemm1Grid, blk, 0, stream,
                       A16, DIM, WT16, b1[0], b1[0],
                       nfm, Braw16, DIM2, stats, DIM2, NNODES, nf, nf, nfm, nfm);
    hipLaunchKernelGGL((bn_apply_kernel<DIM2>), dim3(2048), blk, 0, stream,
                       Braw16, stats, g[0], be[0]);
    hipLaunchKernelGGL((mfma_gemm<DIM2, true, false, false>), gemm2Grid, blk, 0, stream,
                       Braw16, DIM2, WT16 + 4 * 131072, b2[0], b2[0],
                       nfm, H16, DIM, nfm, DIM, NNODES, nf, nf, nfm, nfm);

    // ---------------- layer 1 ----------------
    if (useEa16)
        hipLaunchKernelGGL((agg_kernel<false, true, false>), dim3(aggGrid), blk, 0, stream,
                           (const float*)nullptr, H16, (const float*)nullptr, ea16, (ushort*)nullptr,
                           off, perm_e, perm_s, A16);
    else
        hipLaunchKernelGGL((agg_kernel<false, false, false>), dim3(aggGrid), blk, 0, stream,
                           (const float*)nullptr, H16, ea, (const ushort*)nullptr, (ushort*)nullptr,
                           off, perm_e, perm_s, A16);
    hipLaunchKernelGGL((mfma_gemm<DIM, true, true, false>), gemm1Grid, blk, 0, stream,
                       A16, DIM, WT16 + 1 * 131072, b1[1], b1[1],
                       nfm, Braw16, DIM2, stats + 1024, DIM2, NNODES, nf, nf, nfm, nfm);
    hipLaunchKernelGGL((bn_apply_kernel<DIM2>), dim3(2048), blk, 0, stream,
                       Braw16, stats + 1024, g[1], be[1]);
    hipLaunchKernelGGL((mfma_gemm<DIM2, true, false, false>), gemm2Grid, blk, 0, stream,
                       Braw16, DIM2, WT16 + 5 * 131072, b2[1], b2[1],
                       nfm, H16, DIM, nfm, DIM, NNODES, nf, nf, nfm, nfm);

    // ---------------- layers 2+3 (merged GEMM1; BN folded into GEMM2) --------
    if (useEa16)
        hipLaunchKernelGGL((agg_kernel<false, true, false>), dim3(aggGrid), blk, 0, stream,
                           (const float*)nullptr, H16, (const float*)nullptr, ea16, (ushort*)nullptr,
                           off, perm_e, perm_s, A16);
    else
        hipLaunchKernelGGL((agg_kernel<false, false, false>), dim3(aggGrid), blk, 0, stream,
                           (const float*)nullptr, H16, ea, (const ushort*)nullptr, (ushort*)nullptr,
                           off, perm_e, perm_s, A16);
    hipLaunchKernelGGL((mfma_gemm<DIM, true, true, false>), gemm1WGrid, blk, 0, stream,
                       A16, DIM, WT16 + 2 * 131072, b1[2], b1[3],
                       nfm, Braw16, 1024, stats + 2048, 1024, NNODES, nf, nf, nfm, nfm);
    hipLaunchKernelGGL(wfold_kernel, dim3(512), dim3(64), 0, stream,
                       WT16 + 6 * 131072, WT16 + 7 * 131072, stats + 2048,
                       g[2], be[2], g[3], be[3], b2[2], b2[3], W2f, b2f);
    // mean = Braw16[:,0:512] @ W2f_0 + b2f_0
    hipLaunchKernelGGL((mfma_gemm<DIM2, false, false, false>), gemm2Grid, blk, 0, stream,
                       Braw16, 1024, W2f, b2f, b2f,
                       out + NDTOT, (ushort*)nullptr, DIM, nfm, DIM, NNODES, nf, nf, nfm, nfm);
    // logstd = Braw16[:,512:1024] @ W2f_1 + b2f_1 ; fused z + KL
    hipLaunchKernelGGL((mfma_gemm<DIM2, false, false, true>), gemm2Grid, blk, 0, stream,
                       Braw16 + 512, 1024, W2f + 131072, b2f + 256, b2f + 256,
                       out + 2 * NDTOT, (ushort*)nullptr, DIM, nfm, DIM, NNODES,
                       out + NDTOT, noise, out, klP);
}